// Round 6
// baseline (748.118 us; speedup 1.0000x reference)
//
#include <hip/hip_runtime.h>

#define NN 100000
#define NE 600000
#define DD 128
#define NL 4
#define GB 768  // persistent GEMM grid: 3 blocks/CU x 256 CU

typedef __attribute__((ext_vector_type(8))) short short8;
typedef __attribute__((ext_vector_type(4))) float float4v;
typedef __attribute__((ext_vector_type(2))) float f2;

__device__ inline unsigned short f2bf(float f) {
  union { float f; unsigned u; } v; v.f = f;
  unsigned r = v.u + 0x7fff + ((v.u >> 16) & 1);  // round-to-nearest-even
  return (unsigned short)(r >> 16);
}
__device__ inline float bf2f(unsigned short u) {
  union { unsigned u; float f; } v; v.u = ((unsigned)u) << 16;
  return v.f;
}
__device__ inline f2 bfpair(unsigned u) {
  f2 r;
  r.x = __uint_as_float(u << 16);
  r.y = __uint_as_float(u & 0xffff0000u);
  return r;
}

// ---------------- one-time: W1/W2 -> bf16 transposed [n][k]; zero counts/stats ----
__global__ void k_prep(const float* __restrict__ W1, const float* __restrict__ W2,
                       unsigned short* __restrict__ WT, int* __restrict__ counts,
                       float* __restrict__ stats4) {
  int i = blockIdx.x * 256 + threadIdx.x;  // over 8*16384 = 131072
  if (i < NN) counts[i] = 0;
  if (i < NL * 256) stats4[i] = 0.f;
  if (i >= 8 * 16384) return;
  int m = i >> 14;
  int el = i & 16383;
  int k = el >> 7;
  int n = el & 127;
  const float* src = (m < 4) ? (W1 + (size_t)m * 16384) : (W2 + (size_t)(m - 4) * 16384);
  WT[(size_t)m * 16384 + n * 128 + k] = f2bf(src[k * 128 + n]);
}

// -------- setup: fp32 x -> bf16 mirror, fused edge counting (counts pre-zeroed) ----
__global__ void k_h2b(const float* __restrict__ src, unsigned short* __restrict__ dst,
                      const int* __restrict__ ei, int* __restrict__ counts) {
  int i = blockIdx.x * 256 + threadIdx.x;
  if (i < NE) atomicAdd(&counts[ei[NE + i]], 1);
  if (i >= NN * DD / 4) return;
  float4 v = ((const float4*)src)[i];
  ushort4 o;
  o.x = f2bf(v.x); o.y = f2bf(v.y); o.z = f2bf(v.z); o.w = f2bf(v.w);
  ((ushort4*)dst)[i] = o;
}

// ---------------- CSR build (once per call) ----------------
#define ST 256
#define SC 2
#define SB ((NN + ST * SC - 1) / (ST * SC))  // 196 blocks

__global__ void k_scan_part(const int* __restrict__ counts, int* __restrict__ row_ptr,
                            int* __restrict__ bsums) {
  __shared__ int s[ST];
  int b = blockIdx.x, t = threadIdx.x;
  int base = b * (ST * SC) + t * SC;
  int v0 = (base < NN) ? counts[base] : 0;
  int v1 = (base + 1 < NN) ? counts[base + 1] : 0;
  int tsum = v0 + v1;
  s[t] = tsum;
  __syncthreads();
  for (int d = 1; d < ST; d <<= 1) {
    int x = (t >= d) ? s[t - d] : 0;
    __syncthreads();
    s[t] += x;
    __syncthreads();
  }
  int excl = s[t] - tsum;
  if (base < NN) row_ptr[base] = excl;
  if (base + 1 < NN) row_ptr[base + 1] = excl + v0;
  if (t == ST - 1) bsums[b] = s[t];
}

__global__ void k_scan_bsum(const int* __restrict__ bsums, int* __restrict__ boffs,
                            int* __restrict__ row_ptr) {
  __shared__ int s[ST];
  int t = threadIdx.x;
  int v = (t < SB) ? bsums[t] : 0;
  s[t] = v;
  __syncthreads();
  for (int d = 1; d < ST; d <<= 1) {
    int x = (t >= d) ? s[t - d] : 0;
    __syncthreads();
    s[t] += x;
    __syncthreads();
  }
  if (t < SB) boffs[t] = s[t] - v;
  if (t == ST - 1) row_ptr[NN] = s[t];
}

// finalizes row_ptr and initializes off[] as ABSOLUTE write cursors (= row_ptr)
__global__ void k_scan_add(const int* __restrict__ boffs, int* __restrict__ row_ptr,
                           int* __restrict__ off) {
  int b = blockIdx.x, t = threadIdx.x;
  int base = b * (ST * SC) + t * SC;
  int o = boffs[b];
  if (base < NN) { int v = row_ptr[base] + o; row_ptr[base] = v; off[base] = v; }
  if (base + 1 < NN) { int v = row_ptr[base + 1] + o; row_ptr[base + 1] = v; off[base + 1] = v; }
}

// packed CSR record: .x = src node, .y = attr bits; absolute-cursor atomic
__global__ void k_fill(const int* __restrict__ ei, const float* __restrict__ attr,
                       int* __restrict__ off, int2* __restrict__ csr) {
  int e = blockIdx.x * 256 + threadIdx.x;
  if (e >= NE) return;
  int srcv = ei[e];
  int dstv = ei[NE + e];
  int idx = atomicAdd(&off[dstv], 1);
  csr[idx] = make_int2(srcv, __float_as_int(attr[e]));
}

// ------- aggregation: zb = bf16( (1+eps)*hb[n] + sum relu(hb[src]+attr*We+be) ) -------
__global__ __launch_bounds__(256) void k_agg(
    const unsigned short* __restrict__ hb,
    const int* __restrict__ row_ptr, const int2* __restrict__ csr,
    const float* __restrict__ We, const float* __restrict__ be,
    const float* __restrict__ epsp, unsigned short* __restrict__ zb) {
  const int tid0 = blockIdx.x * 256 + threadIdx.x;
  const int li = tid0 & 15;
  const int g0 = tid0 >> 4;
  const int NG = (gridDim.x * 256) >> 4;
  const int d0 = li * 8;

  const f2 we01 = *(const f2*)(We + d0);
  const f2 we23 = *(const f2*)(We + d0 + 2);
  const f2 we45 = *(const f2*)(We + d0 + 4);
  const f2 we67 = *(const f2*)(We + d0 + 6);
  const f2 be01 = *(const f2*)(be + d0);
  const f2 be23 = *(const f2*)(be + d0 + 2);
  const f2 be45 = *(const f2*)(be + d0 + 4);
  const f2 be67 = *(const f2*)(be + d0 + 6);
  const float ep = 1.f + epsp[0];
  f2 ep2; ep2.x = ep; ep2.y = ep;
  const f2 zero2 = {0.f, 0.f};

  int n = g0;
  if (n >= NN) return;
  int b = row_ptr[n], e = row_ptr[n + 1];
  int cnt = min(e - b, 16);
  int2 rec = (li < cnt) ? csr[b + li] : make_int2(0, 0);

  while (n < NN) {
    const int n2 = n + NG;
    int b2 = 0, e2 = 0;
    if (n2 < NN) { b2 = row_ptr[n2]; e2 = row_ptr[n2 + 1]; }  // prefetch next rowptr
    uint4 hs = *(const uint4*)(hb + (size_t)n * DD + d0);     // self term (early issue)

    const int myidx = rec.x;
    const float myatt = __int_as_float(rec.y);
    f2 a01 = zero2, a23 = zero2, a45 = zero2, a67 = zero2;

#define CONS8(hv, at)                                                         \
    do {                                                                      \
      f2 av; av.x = (at); av.y = (at);                                        \
      f2 e01 = av * we01 + be01, e23 = av * we23 + be23;                      \
      f2 e45 = av * we45 + be45, e67 = av * we67 + be67;                      \
      f2 s;                                                                   \
      s = bfpair((hv).x) + e01; a01 += __builtin_elementwise_max(s, zero2);   \
      s = bfpair((hv).y) + e23; a23 += __builtin_elementwise_max(s, zero2);   \
      s = bfpair((hv).z) + e45; a45 += __builtin_elementwise_max(s, zero2);   \
      s = bfpair((hv).w) + e67; a67 += __builtin_elementwise_max(s, zero2);   \
    } while (0)

    int i = 0;
    for (; i + 4 <= cnt; i += 4) {
      int s0 = __shfl(myidx, i, 16);
      int s1 = __shfl(myidx, i + 1, 16);
      int s2 = __shfl(myidx, i + 2, 16);
      int s3 = __shfl(myidx, i + 3, 16);
      float a0 = __shfl(myatt, i, 16);
      float a1 = __shfl(myatt, i + 1, 16);
      float a2 = __shfl(myatt, i + 2, 16);
      float a3 = __shfl(myatt, i + 3, 16);
      uint4 hv0 = *(const uint4*)(hb + (size_t)s0 * DD + d0);
      uint4 hv1 = *(const uint4*)(hb + (size_t)s1 * DD + d0);
      uint4 hv2 = *(const uint4*)(hb + (size_t)s2 * DD + d0);
      uint4 hv3 = *(const uint4*)(hb + (size_t)s3 * DD + d0);
      CONS8(hv0, a0);
      CONS8(hv1, a1);
      CONS8(hv2, a2);
      CONS8(hv3, a3);
    }
    for (; i < cnt; i++) {
      int s = __shfl(myidx, i, 16);
      float a = __shfl(myatt, i, 16);
      uint4 hv = *(const uint4*)(hb + (size_t)s * DD + d0);
      CONS8(hv, a);
    }
    // degree > 16 tail (rare; correctness fallback)
    for (int j = b + 16; j < e; j++) {
      int2 r2 = csr[j];
      float a = __int_as_float(r2.y);
      uint4 hv = *(const uint4*)(hb + (size_t)r2.x * DD + d0);
      CONS8(hv, a);
    }
#undef CONS8

    // prefetch next node's CSR record (overlaps epilogue + next rowptr wait)
    int cnt2 = min(e2 - b2, 16);
    int2 rec2 = (n2 < NN && li < cnt2) ? csr[b2 + li] : make_int2(0, 0);

    f2 z01 = ep2 * bfpair(hs.x) + a01;
    f2 z23 = ep2 * bfpair(hs.y) + a23;
    f2 z45 = ep2 * bfpair(hs.z) + a45;
    f2 z67 = ep2 * bfpair(hs.w) + a67;
    uint4 o;
    o.x = (unsigned)f2bf(z01.x) | ((unsigned)f2bf(z01.y) << 16);
    o.y = (unsigned)f2bf(z23.x) | ((unsigned)f2bf(z23.y) << 16);
    o.z = (unsigned)f2bf(z45.x) | ((unsigned)f2bf(z45.y) << 16);
    o.w = (unsigned)f2bf(z67.x) | ((unsigned)f2bf(z67.y) << 16);
    *(uint4*)(zb + (size_t)n * DD + d0) = o;

    n = n2; b = b2; e = e2; cnt = cnt2; rec = rec2;
  }
}

// ---------------- persistent MFMA bf16 GEMM, W-in-VGPR, column-split waves ------
// Wave w owns output cols [32w, 32w+32): its 32 W^T fragments live in VGPRs
// (loaded once), so LDS holds only the double-buffered X tile -> 36 KB ->
// 3 blocks/CU (vs 2), and 16 ds_read_b128/tile (vs 36).
// Each wave computes all 64 rows x its 32 cols: acc[rb][cti], 32 MFMAs/tile.
// D layout: lane(m,quad) of MFMA(rb,cti) holds rows rb*16+m? no: col=lane&15 -> X row,
//   row=quad*4+reg -> W^T row = output col. So thread stores row rb*16+m? See epilogue:
//   output row r = t*64 + rb*16 + m, output cols w*32 + cti*16 + quad*4 + reg.
// MODE 0: z2(bf16) = Xb@W + b, fused column stats (sum,sumsq) -> stats[256]
// MODE 1: Y = relu( relu(bn(Xb))@W + b );       Ybf = bf16(Y) if non-null
// MODE 2: Y = hprev + relu( relu(bn(Xb))@W + b ); same mirror (hprev==Y safe)
template <int MODE>
__global__ __launch_bounds__(256, 3) void k_gemm(
    const unsigned short* __restrict__ Xb, const unsigned short* __restrict__ WT,
    const float* __restrict__ bias, float* __restrict__ stats,
    const float* __restrict__ gamma, const float* __restrict__ beta,
    const float* __restrict__ hprev, float* __restrict__ Yout,
    unsigned short* __restrict__ Ybf) {
  __shared__ unsigned short Xl[2][64 * 136];   // 2 x 17408 B
  __shared__ float bns[256];                   // 1024 B -> total 35840 B
  const int tid = threadIdx.x;
  const int G = gridDim.x;
  const int NT = (NN + 63) >> 6;  // 1563

  const int lane = tid & 63;
  const int w = tid >> 6;
  const int m = lane & 15;
  const int quad = lane >> 4;

  // per-wave W fragments: A row = out col = w*32 + cti*16 + m, k = quad*8 + q*32
  short8 wf[2][4];
#pragma unroll
  for (int cti = 0; cti < 2; cti++)
#pragma unroll
    for (int q = 0; q < 4; q++)
      wf[cti][q] =
          *(const short8*)&WT[(size_t)(w * 32 + cti * 16 + m) * 128 + quad * 8 + q * 32];

  float4 b4[2];
#pragma unroll
  for (int cti = 0; cti < 2; cti++)
    b4[cti] = *(const float4*)&bias[w * 32 + cti * 16 + quad * 4];

  // staging mapping: 16B bf16 chunks; c8 = chunk, rows rr16 + it*16
  const int c8 = tid & 15, rr16 = tid >> 4;
  float scl[8], sfl[8];
  if (MODE >= 1) {
    if (tid < 128) {
      const float invN = 1.f / (float)NN;
      float mu = stats[tid] * invN;
      float var = fmaxf(stats[128 + tid] * invN - mu * mu, 0.f);
      float xx = var + 1e-5f;
      float r = rsqrtf(xx);
      r = r * (1.5f - 0.5f * xx * r * r);  // Newton step
      float scale = gamma[tid] * r;
      bns[tid] = scale;
      bns[128 + tid] = beta[tid] - mu * scale;
    }
    __syncthreads();
#pragma unroll
    for (int j = 0; j < 8; j++) {
      scl[j] = bns[c8 * 8 + j];
      sfl[j] = bns[128 + c8 * 8 + j];
    }
  }

  uint4 xu[4];  // prefetch regs (8 bf16 each)
  auto LOADR = [&](int t) {
    int r0 = t << 6;
#pragma unroll
    for (int it = 0; it < 4; it++) {
      int gr = r0 + rr16 + it * 16;
      xu[it] = (gr < NN) ? *(const uint4*)(Xb + (size_t)gr * DD + c8 * 8)
                         : make_uint4(0u, 0u, 0u, 0u);
    }
  };
  auto STORE_LDS = [&](int b) {
#pragma unroll
    for (int it = 0; it < 4; it++) {
      int row = rr16 + it * 16;
      uint4 u = xu[it];
      if (MODE >= 1) {
        unsigned p[4] = {u.x, u.y, u.z, u.w};
#pragma unroll
        for (int j = 0; j < 4; j++) {
          float lo = bf2f((unsigned short)(p[j] & 0xffffu));
          float hi = bf2f((unsigned short)(p[j] >> 16));
          lo = fmaxf(fmaf(lo, scl[2 * j], sfl[2 * j]), 0.f);
          hi = fmaxf(fmaf(hi, scl[2 * j + 1], sfl[2 * j + 1]), 0.f);
          p[j] = (unsigned)f2bf(lo) | ((unsigned)f2bf(hi) << 16);
        }
        u = make_uint4(p[0], p[1], p[2], p[3]);
      }
      *(uint4*)&Xl[b][row * 136 + c8 * 8] = u;
    }
  };

  float4v ssum[2], ssq[2];
  if (MODE == 0) {
#pragma unroll
    for (int cti = 0; cti < 2; cti++) {
      ssum[cti] = (float4v){0.f, 0.f, 0.f, 0.f};
      ssq[cti] = (float4v){0.f, 0.f, 0.f, 0.f};
    }
  }

  const int t0 = blockIdx.x;
  LOADR(t0);
  STORE_LDS(0);
  if (t0 + G < NT) LOADR(t0 + G);
  __syncthreads();  // Xl[0] ready

  int buf = 0;
  for (int t = t0; t < NT; t += G) {
    const int nxt = t + G;
    if (nxt < NT) {
      STORE_LDS(buf ^ 1);                 // regs hold tile nxt (loaded last iter)
      if (nxt + G < NT) LOADR(nxt + G);   // prefetch tile nxt+G
    }

    float4v acc[4][2];
#pragma unroll
    for (int rb = 0; rb < 4; rb++) {
      acc[rb][0] = (float4v){b4[0].x, b4[0].y, b4[0].z, b4[0].w};
      acc[rb][1] = (float4v){b4[1].x, b4[1].y, b4[1].z, b4[1].w};
    }

    const unsigned short* Bp = &Xl[buf][m * 136 + quad * 8];
#pragma unroll
    for (int q = 0; q < 4; q++) {
#pragma unroll
      for (int rb = 0; rb < 4; rb++) {
        short8 bfrag = *(const short8*)(Bp + rb * 16 * 136 + q * 32);
        acc[rb][0] = __builtin_amdgcn_mfma_f32_16x16x32_bf16(wf[0][q], bfrag, acc[rb][0], 0, 0, 0);
        acc[rb][1] = __builtin_amdgcn_mfma_f32_16x16x32_bf16(wf[1][q], bfrag, acc[rb][1], 0, 0, 0);
      }
    }

    // LDS-only fence; epilogue global stores stay in flight across tiles.
    asm volatile("s_waitcnt lgkmcnt(0)" ::: "memory");
    __builtin_amdgcn_s_barrier();

    const int rB = (t << 6) + m;
    const int colB = w * 32 + quad * 4;
    float4 hp[4][2];
    if (MODE == 2) {  // batch-issue residual loads; latency hides under epilogue math
#pragma unroll
      for (int rb = 0; rb < 4; rb++) {
        int r = rB + rb * 16;
        if (r < NN) {
          hp[rb][0] = *(const float4*)&hprev[(size_t)r * DD + colB];
          hp[rb][1] = *(const float4*)&hprev[(size_t)r * DD + colB + 16];
        }
      }
    }
#pragma unroll
    for (int rb = 0; rb < 4; rb++) {
      int r = rB + rb * 16;
      if (r >= NN) continue;
      const size_t rbase = (size_t)r * DD + colB;
#pragma unroll
      for (int cti = 0; cti < 2; cti++) {
        float4v v = acc[rb][cti];
        if (MODE == 0) {
          ssum[cti] += v;
          ssq[cti] += v * v;
          ushort4 o;
          o.x = f2bf(v[0]); o.y = f2bf(v[1]); o.z = f2bf(v[2]); o.w = f2bf(v[3]);
          *(ushort4*)&Ybf[rbase + cti * 16] = o;
        } else {
          v[0] = fmaxf(v[0], 0.f); v[1] = fmaxf(v[1], 0.f);
          v[2] = fmaxf(v[2], 0.f); v[3] = fmaxf(v[3], 0.f);
          if (MODE == 2) {
            float4 h4 = hp[rb][cti];
            v[0] += h4.x; v[1] += h4.y; v[2] += h4.z; v[3] += h4.w;
          }
          *(float4v*)&Yout[rbase + cti * 16] = v;
          if (Ybf) {
            ushort4 o;
            o.x = f2bf(v[0]); o.y = f2bf(v[1]); o.z = f2bf(v[2]); o.w = f2bf(v[3]);
            *(ushort4*)&Ybf[rbase + cti * 16] = o;
          }
        }
      }
    }
    buf ^= 1;
  }

  if (MODE == 0) {
    // wave-disjoint columns: reduce over the 16 m-lanes, then direct atomics.
#pragma unroll
    for (int cti = 0; cti < 2; cti++) {
      float4v s = ssum[cti], s2 = ssq[cti];
#pragma unroll
      for (int d = 1; d < 16; d <<= 1) {
#pragma unroll
        for (int j = 0; j < 4; j++) {
          s[j] += __shfl_xor(s[j], d);
          s2[j] += __shfl_xor(s2[j], d);
        }
      }
      if (m == 0) {
        int cb = w * 32 + cti * 16 + quad * 4;
#pragma unroll
        for (int j = 0; j < 4; j++) {
          atomicAdd(&stats[cb + j], s[j]);
          atomicAdd(&stats[128 + cb + j], s2[j]);
        }
      }
    }
  }
}

// ---------------- driver ----------------
static inline size_t align256(size_t x) { return (x + 255) & ~(size_t)255; }

extern "C" void kernel_launch(void* const* d_in, const int* in_sizes, int n_in,
                              void* d_out, int out_size, void* d_ws, size_t ws_size,
                              hipStream_t stream) {
  const float* x     = (const float*)d_in[0];
  const int*   ei    = (const int*)d_in[1];
  const float* attr  = (const float*)d_in[2];
  const float* We    = (const float*)d_in[3];
  const float* be    = (const float*)d_in[4];
  const float* eps   = (const float*)d_in[5];
  const float* W1    = (const float*)d_in[6];
  const float* b1    = (const float*)d_in[7];
  const float* gamma = (const float*)d_in[8];
  const float* beta  = (const float*)d_in[9];
  const float* W2    = (const float*)d_in[10];
  const float* b2    = (const float*)d_in[11];
  float* out = (float*)d_out;

  char* w = (char*)d_ws;
  unsigned short* z2 = (unsigned short*)w; w += align256((size_t)NN * DD * 2);
  unsigned short* hb = (unsigned short*)w; w += align256((size_t)NN * DD * 2);
  unsigned short* zb = (unsigned short*)w; w += align256((size_t)NN * DD * 2);
  int*   row_ptr  = (int*)w;   w += align256((size_t)(NN + 1) * 4);
  int*   counts   = (int*)w;   w += align256((size_t)NN * 4);
  int*   off      = (int*)w;   w += align256((size_t)NN * 4);
  int2*  csr      = (int2*)w;  w += align256((size_t)NE * 8);
  float* stats4   = (float*)w; w += align256((size_t)NL * 256 * 4);
  int*   bsums    = (int*)w;   w += align256(ST * 4);
  int*   boffs    = (int*)w;   w += align256(ST * 4);
  unsigned short* WTb = (unsigned short*)w; w += align256((size_t)8 * 16384 * 2);

  // weight prep (zeroes counts+stats) -> h2b (fused edge count) -> CSR build
  k_prep<<<512, 256, 0, stream>>>(W1, W2, WTb, counts, stats4);
  k_h2b<<<(NN * DD / 4 + 255) / 256, 256, 0, stream>>>(x, hb, ei, counts);
  k_scan_part<<<SB, ST, 0, stream>>>(counts, row_ptr, bsums);
  k_scan_bsum<<<1, ST, 0, stream>>>(bsums, boffs, row_ptr);
  k_scan_add<<<SB, ST, 0, stream>>>(boffs, row_ptr, off);
  k_fill<<<(NE + 255) / 256, 256, 0, stream>>>(ei, attr, off, csr);

  for (int l = 0; l < NL; l++) {
    float* st = stats4 + (size_t)l * 256;
    k_agg<<<1024, 256, 0, stream>>>(
        hb, row_ptr, csr, We + l * DD, be + l * DD, eps + l, zb);
    // z2(bf16) = zb @ W1 + b1, fused stats
    k_gemm<0><<<GB, 256, 0, stream>>>(zb, WTb + (size_t)l * 16384, b1 + l * DD,
                                      st, nullptr, nullptr, nullptr, nullptr, z2);
    unsigned short* hbo = (l < NL - 1) ? hb : nullptr;
    if (l == 0)
      k_gemm<1><<<GB, 256, 0, stream>>>(z2, WTb + (size_t)(4 + l) * 16384, b2 + l * DD,
                                        st, gamma + l * DD, beta + l * DD,
                                        nullptr, out, hbo);
    else
      k_gemm<2><<<GB, 256, 0, stream>>>(z2, WTb + (size_t)(4 + l) * 16384, b2 + l * DD,
                                        st, gamma + l * DD, beta + l * DD,
                                        out, out, hbo);
  }
}

// Round 7
// 659.856 us; speedup vs baseline: 1.1338x; 1.1338x over previous
//
#include <hip/hip_runtime.h>

#define NN 100000
#define NE 600000
#define DD 128
#define NL 4
#define GB 512  // persistent GEMM grid: 2 blocks/CU x 256 CU

typedef __attribute__((ext_vector_type(8))) short short8;
typedef __attribute__((ext_vector_type(4))) float float4v;
typedef __attribute__((ext_vector_type(2))) float f2;

__device__ inline unsigned short f2bf(float f) {
  union { float f; unsigned u; } v; v.f = f;
  unsigned r = v.u + 0x7fff + ((v.u >> 16) & 1);  // round-to-nearest-even
  return (unsigned short)(r >> 16);
}
__device__ inline float bf2f(unsigned short u) {
  union { unsigned u; float f; } v; v.u = ((unsigned)u) << 16;
  return v.f;
}
__device__ inline f2 bfpair(unsigned u) {
  f2 r;
  r.x = __uint_as_float(u << 16);
  r.y = __uint_as_float(u & 0xffff0000u);
  return r;
}

// ---------------- one-time: W1/W2 -> bf16 transposed [n][k]; zero counts/stats ----
__global__ void k_prep(const float* __restrict__ W1, const float* __restrict__ W2,
                       unsigned short* __restrict__ WT, int* __restrict__ counts,
                       float* __restrict__ stats4) {
  int i = blockIdx.x * 256 + threadIdx.x;  // over 8*16384 = 131072
  if (i < NN) counts[i] = 0;
  if (i < NL * 256) stats4[i] = 0.f;
  if (i >= 8 * 16384) return;
  int m = i >> 14;
  int el = i & 16383;
  int k = el >> 7;
  int n = el & 127;
  const float* src = (m < 4) ? (W1 + (size_t)m * 16384) : (W2 + (size_t)(m - 4) * 16384);
  WT[(size_t)m * 16384 + n * 128 + k] = f2bf(src[k * 128 + n]);
}

// -------- setup: fp32 x -> bf16 mirror, fused edge counting (counts pre-zeroed) ----
__global__ void k_h2b(const float* __restrict__ src, unsigned short* __restrict__ dst,
                      const int* __restrict__ ei, int* __restrict__ counts) {
  int i = blockIdx.x * 256 + threadIdx.x;
  if (i < NE) atomicAdd(&counts[ei[NE + i]], 1);
  if (i >= NN * DD / 4) return;
  float4 v = ((const float4*)src)[i];
  ushort4 o;
  o.x = f2bf(v.x); o.y = f2bf(v.y); o.z = f2bf(v.z); o.w = f2bf(v.w);
  ((ushort4*)dst)[i] = o;
}

// ---------------- CSR build (once per call) ----------------
#define ST 256
#define SC 2
#define SB ((NN + ST * SC - 1) / (ST * SC))  // 196 blocks

__global__ void k_scan_part(const int* __restrict__ counts, int* __restrict__ row_ptr,
                            int* __restrict__ bsums) {
  __shared__ int s[ST];
  int b = blockIdx.x, t = threadIdx.x;
  int base = b * (ST * SC) + t * SC;
  int v0 = (base < NN) ? counts[base] : 0;
  int v1 = (base + 1 < NN) ? counts[base + 1] : 0;
  int tsum = v0 + v1;
  s[t] = tsum;
  __syncthreads();
  for (int d = 1; d < ST; d <<= 1) {
    int x = (t >= d) ? s[t - d] : 0;
    __syncthreads();
    s[t] += x;
    __syncthreads();
  }
  int excl = s[t] - tsum;
  if (base < NN) row_ptr[base] = excl;
  if (base + 1 < NN) row_ptr[base + 1] = excl + v0;
  if (t == ST - 1) bsums[b] = s[t];
}

__global__ void k_scan_bsum(const int* __restrict__ bsums, int* __restrict__ boffs,
                            int* __restrict__ row_ptr) {
  __shared__ int s[ST];
  int t = threadIdx.x;
  int v = (t < SB) ? bsums[t] : 0;
  s[t] = v;
  __syncthreads();
  for (int d = 1; d < ST; d <<= 1) {
    int x = (t >= d) ? s[t - d] : 0;
    __syncthreads();
    s[t] += x;
    __syncthreads();
  }
  if (t < SB) boffs[t] = s[t] - v;
  if (t == ST - 1) row_ptr[NN] = s[t];
}

// finalizes row_ptr and initializes off[] as ABSOLUTE write cursors (= row_ptr)
__global__ void k_scan_add(const int* __restrict__ boffs, int* __restrict__ row_ptr,
                           int* __restrict__ off) {
  int b = blockIdx.x, t = threadIdx.x;
  int base = b * (ST * SC) + t * SC;
  int o = boffs[b];
  if (base < NN) { int v = row_ptr[base] + o; row_ptr[base] = v; off[base] = v; }
  if (base + 1 < NN) { int v = row_ptr[base + 1] + o; row_ptr[base + 1] = v; off[base + 1] = v; }
}

// packed CSR record: .x = src node, .y = attr bits; absolute-cursor atomic
__global__ void k_fill(const int* __restrict__ ei, const float* __restrict__ attr,
                       int* __restrict__ off, int2* __restrict__ csr) {
  int e = blockIdx.x * 256 + threadIdx.x;
  if (e >= NE) return;
  int srcv = ei[e];
  int dstv = ei[NE + e];
  int idx = atomicAdd(&off[dstv], 1);
  csr[idx] = make_int2(srcv, __float_as_int(attr[e]));
}

// consume one gathered neighbor row (8 features in hv) into the f2 accumulators
#define CONS8(hv, at)                                                         \
  do {                                                                        \
    f2 av; av.x = (at); av.y = (at);                                          \
    f2 sx;                                                                    \
    sx = bfpair((hv).x) + (av * we01 + be01);                                 \
    a01 += __builtin_elementwise_max(sx, zero2);                              \
    sx = bfpair((hv).y) + (av * we23 + be23);                                 \
    a23 += __builtin_elementwise_max(sx, zero2);                              \
    sx = bfpair((hv).z) + (av * we45 + be45);                                 \
    a45 += __builtin_elementwise_max(sx, zero2);                              \
    sx = bfpair((hv).w) + (av * we67 + be67);                                 \
    a67 += __builtin_elementwise_max(sx, zero2);                              \
  } while (0)

// ---------------- persistent double-buffered MFMA bf16 GEMM (R5 structure) --------
// Operand-swapped (A = W^T tile in LDS, B = X rows): lane owns ONE output row,
// 4 consecutive cols per ct chunk -> float4 epilogue. Per-tile sync is
// lgkmcnt(0)+s_barrier only; epilogue global stores stay in flight across tiles.
// MODE 0: FUSED GINE aggregation in staging: for each X row (= node), gather its
//         CSR neighbors from hb, z = (1+eps)*hb[n] + sum relu(hb[src]+attr*We+be),
//         pack bf16 -> LDS. Then z2(bf16) = Z@W1 + b1 with fused column stats.
//         (16 staging lanes per row == 16-lane-per-node agg groups; width-16 shfl.)
// MODE 1: Y = relu( relu(bn(Xb))@W + b );       Ybf = bf16(Y) if non-null
// MODE 2: Y = hprev + relu( relu(bn(Xb))@W + b ); same mirror (hprev==Y safe)
// MODE 1/2 compute BN scale/shift from stats+gamma+beta in-kernel (per block).
template <int MODE>
__global__ __launch_bounds__(256, 2) void k_gemm(
    const unsigned short* __restrict__ Xb, const unsigned short* __restrict__ WT,
    const float* __restrict__ bias, float* __restrict__ stats,
    const float* __restrict__ gamma, const float* __restrict__ beta,
    const float* __restrict__ hprev, float* __restrict__ Yout,
    unsigned short* __restrict__ Ybf,
    const unsigned short* __restrict__ hb, const int* __restrict__ row_ptr,
    const int2* __restrict__ csr, const float* __restrict__ We,
    const float* __restrict__ be, const float* __restrict__ epsp) {
  __shared__ unsigned short Wl[128 * 136];     // 34816 B
  __shared__ unsigned short Xl[2][64 * 136];   // 2 x 17408 B
  __shared__ float bns[256];                   // 1024 B -> total 70656 B, 2 blk/CU
  const int tid = threadIdx.x;
  const int G = gridDim.x;
  const int NT = (NN + 63) >> 6;  // 1563

  // stage W^T bf16 [n][k] -> LDS, once per block
  for (int i = tid; i < 2048; i += 256) {
    int rr = i >> 4, c = i & 15;
    *(uint4*)&Wl[rr * 136 + c * 8] = *(const uint4*)&WT[rr * 128 + c * 8];
  }

  const int lane = tid & 63;
  const int w = tid >> 6;
  const int m = lane & 15;
  const int quad = lane >> 4;

  // staging mapping: 16B bf16 chunks; c8 = staging lane (0..15), rows rr16 + it*16
  const int c8 = tid & 15, rr16 = tid >> 4;
  const f2 zero2 = {0.f, 0.f};

  // MODE0 fused-agg constants: this staging lane owns features d0..d0+7
  f2 we01 = zero2, we23 = zero2, we45 = zero2, we67 = zero2;
  f2 be01 = zero2, be23 = zero2, be45 = zero2, be67 = zero2;
  f2 ep2 = zero2;
  if (MODE == 0) {
    const int d0 = c8 * 8;
    we01 = *(const f2*)(We + d0);
    we23 = *(const f2*)(We + d0 + 2);
    we45 = *(const f2*)(We + d0 + 4);
    we67 = *(const f2*)(We + d0 + 6);
    be01 = *(const f2*)(be + d0);
    be23 = *(const f2*)(be + d0 + 2);
    be45 = *(const f2*)(be + d0 + 4);
    be67 = *(const f2*)(be + d0 + 6);
    float ep = 1.f + epsp[0];
    ep2.x = ep; ep2.y = ep;
  }

  float scl[8], sfl[8];
  if (MODE >= 1) {
    if (tid < 128) {
      const float invN = 1.f / (float)NN;
      float mu = stats[tid] * invN;
      float var = fmaxf(stats[128 + tid] * invN - mu * mu, 0.f);
      float xx = var + 1e-5f;
      float r = rsqrtf(xx);
      r = r * (1.5f - 0.5f * xx * r * r);  // Newton step
      float scale = gamma[tid] * r;
      bns[tid] = scale;
      bns[128 + tid] = beta[tid] - mu * scale;
    }
    __syncthreads();
#pragma unroll
    for (int j = 0; j < 8; j++) {
      scl[j] = bns[c8 * 8 + j];
      sfl[j] = bns[128 + c8 * 8 + j];
    }
  }

  uint4 xu[4];  // staged rows (8 bf16 each): loaded (MODE>=1) or aggregated (MODE 0)
  auto LOADR = [&](int t) {
    int r0 = t << 6;
#pragma unroll
    for (int it = 0; it < 4; it++) {
      int gr = r0 + rr16 + it * 16;  // group-uniform across the 16 staging lanes
      if (MODE == 0) {
        uint4 o = make_uint4(0u, 0u, 0u, 0u);
        if (gr < NN) {
          const int d0 = c8 * 8;
          int b = row_ptr[gr], e = row_ptr[gr + 1];
          int cnt = min(e - b, 16);
          int2 rec = (c8 < cnt) ? csr[b + c8] : make_int2(0, 0);
          f2 a01 = zero2, a23 = zero2, a45 = zero2, a67 = zero2;
          for (int i = 0; i < cnt; i++) {
            int s = __shfl(rec.x, i, 16);
            float a = __int_as_float(__shfl(rec.y, i, 16));
            uint4 hv = *(const uint4*)(hb + (size_t)s * DD + d0);
            CONS8(hv, a);
          }
          // degree > 16 tail (rare; correctness fallback)
          for (int j = b + 16; j < e; j++) {
            int2 r2 = csr[j];
            float a = __int_as_float(r2.y);
            uint4 hv = *(const uint4*)(hb + (size_t)r2.x * DD + d0);
            CONS8(hv, a);
          }
          uint4 hs = *(const uint4*)(hb + (size_t)gr * DD + d0);
          f2 z01 = ep2 * bfpair(hs.x) + a01;
          f2 z23 = ep2 * bfpair(hs.y) + a23;
          f2 z45 = ep2 * bfpair(hs.z) + a45;
          f2 z67 = ep2 * bfpair(hs.w) + a67;
          o.x = (unsigned)f2bf(z01.x) | ((unsigned)f2bf(z01.y) << 16);
          o.y = (unsigned)f2bf(z23.x) | ((unsigned)f2bf(z23.y) << 16);
          o.z = (unsigned)f2bf(z45.x) | ((unsigned)f2bf(z45.y) << 16);
          o.w = (unsigned)f2bf(z67.x) | ((unsigned)f2bf(z67.y) << 16);
        }
        xu[it] = o;
      } else {
        xu[it] = (gr < NN) ? *(const uint4*)(Xb + (size_t)gr * DD + c8 * 8)
                           : make_uint4(0u, 0u, 0u, 0u);
      }
    }
  };
  auto STORE_LDS = [&](int b) {
#pragma unroll
    for (int it = 0; it < 4; it++) {
      int row = rr16 + it * 16;
      uint4 u = xu[it];
      if (MODE >= 1) {
        unsigned p[4] = {u.x, u.y, u.z, u.w};
#pragma unroll
        for (int j = 0; j < 4; j++) {
          float lo = bf2f((unsigned short)(p[j] & 0xffffu));
          float hi = bf2f((unsigned short)(p[j] >> 16));
          lo = fmaxf(fmaf(lo, scl[2 * j], sfl[2 * j]), 0.f);
          hi = fmaxf(fmaf(hi, scl[2 * j + 1], sfl[2 * j + 1]), 0.f);
          p[j] = (unsigned)f2bf(lo) | ((unsigned)f2bf(hi) << 16);
        }
        u = make_uint4(p[0], p[1], p[2], p[3]);
      }
      *(uint4*)&Xl[b][row * 136 + c8 * 8] = u;
    }
  };

  float4v ssum[8], ssq[8];
  if (MODE == 0) {
#pragma unroll
    for (int ct = 0; ct < 8; ct++) {
      ssum[ct] = (float4v){0.f, 0.f, 0.f, 0.f};
      ssq[ct] = (float4v){0.f, 0.f, 0.f, 0.f};
    }
  }

  const int t0 = blockIdx.x;
  LOADR(t0);
  STORE_LDS(0);
  if (t0 + G < NT) LOADR(t0 + G);
  __syncthreads();  // Xl[0] + Wl ready

  int buf = 0;
  for (int t = t0; t < NT; t += G) {
    const int nxt = t + G;
    if (nxt < NT) {
      STORE_LDS(buf ^ 1);                 // regs hold tile nxt (built last iter)
      if (nxt + G < NT) LOADR(nxt + G);   // prefetch/aggregate tile nxt+G
    }

    float4v acc[8];
#pragma unroll
    for (int ct = 0; ct < 8; ct++) {
      float4 b4 = *(const float4*)&bias[ct * 16 + quad * 4];
      acc[ct] = (float4v){b4.x, b4.y, b4.z, b4.w};
    }

    // A = W^T rows (output cols), B = X rows (output rows in lanes)
    const unsigned short* Ap = &Wl[m * 136 + quad * 8];
    const unsigned short* Bp = &Xl[buf][(w * 16 + m) * 136 + quad * 8];
#pragma unroll
    for (int q = 0; q < 4; q++) {
      short8 bfrag = *(const short8*)(Bp + q * 32);
#pragma unroll
      for (int ct = 0; ct < 8; ct++) {
        short8 afrag = *(const short8*)(Ap + ct * 16 * 136 + q * 32);
        acc[ct] = __builtin_amdgcn_mfma_f32_16x16x32_bf16(afrag, bfrag, acc[ct], 0, 0, 0);
      }
    }

    // LDS-only fence; epilogue global stores stay in flight across tiles.
    asm volatile("s_waitcnt lgkmcnt(0)" ::: "memory");
    __builtin_amdgcn_s_barrier();

    const int r = (t << 6) + w * 16 + m;  // this lane's output row
    if (r < NN) {
      const size_t rb = (size_t)r * DD;
#pragma unroll
      for (int ct = 0; ct < 8; ct++) {
        float4v v = acc[ct];
        const int col = ct * 16 + quad * 4;
        if (MODE == 0) {
          ssum[ct] += v;
          ssq[ct] += v * v;
          ushort4 o;
          o.x = f2bf(v[0]); o.y = f2bf(v[1]); o.z = f2bf(v[2]); o.w = f2bf(v[3]);
          *(ushort4*)&Ybf[rb + col] = o;
        } else {
          v[0] = fmaxf(v[0], 0.f); v[1] = fmaxf(v[1], 0.f);
          v[2] = fmaxf(v[2], 0.f); v[3] = fmaxf(v[3], 0.f);
          if (MODE == 2) {
            float4 hp = *(const float4*)&hprev[rb + col];
            v[0] += hp.x; v[1] += hp.y; v[2] += hp.z; v[3] += hp.w;
          }
          *(float4v*)&Yout[rb + col] = v;
          if (Ybf) {
            ushort4 o;
            o.x = f2bf(v[0]); o.y = f2bf(v[1]); o.z = f2bf(v[2]); o.w = f2bf(v[3]);
            *(ushort4*)&Ybf[rb + col] = o;
          }
        }
      }
    }
    buf ^= 1;
  }

  if (MODE == 0) {
    // per-lane col sums: reduce over the 16 lanes (m) of each quad, then waves via LDS.
    float* sarr = (float*)Xl;   // [4][128]
    float* sqarr = sarr + 512;  // [4][128]
#pragma unroll
    for (int ct = 0; ct < 8; ct++) {
      float4v s = ssum[ct], s2 = ssq[ct];
#pragma unroll
      for (int d = 1; d < 16; d <<= 1) {
#pragma unroll
        for (int j = 0; j < 4; j++) {
          s[j] += __shfl_xor(s[j], d);
          s2[j] += __shfl_xor(s2[j], d);
        }
      }
      if (m == 0) {
        *(float4v*)&sarr[w * 128 + ct * 16 + quad * 4] = s;
        *(float4v*)&sqarr[w * 128 + ct * 16 + quad * 4] = s2;
      }
    }
    __syncthreads();
    if (tid < 128) {
      atomicAdd(&stats[tid], sarr[tid] + sarr[128 + tid] + sarr[256 + tid] + sarr[384 + tid]);
    } else {
      int c = tid - 128;
      atomicAdd(&stats[128 + c], sqarr[c] + sqarr[128 + c] + sqarr[256 + c] + sqarr[384 + c]);
    }
  }
}

// ---------------- driver ----------------
static inline size_t align256(size_t x) { return (x + 255) & ~(size_t)255; }

extern "C" void kernel_launch(void* const* d_in, const int* in_sizes, int n_in,
                              void* d_out, int out_size, void* d_ws, size_t ws_size,
                              hipStream_t stream) {
  const float* x     = (const float*)d_in[0];
  const int*   ei    = (const int*)d_in[1];
  const float* attr  = (const float*)d_in[2];
  const float* We    = (const float*)d_in[3];
  const float* be    = (const float*)d_in[4];
  const float* eps   = (const float*)d_in[5];
  const float* W1    = (const float*)d_in[6];
  const float* b1    = (const float*)d_in[7];
  const float* gamma = (const float*)d_in[8];
  const float* beta  = (const float*)d_in[9];
  const float* W2    = (const float*)d_in[10];
  const float* b2    = (const float*)d_in[11];
  float* out = (float*)d_out;

  char* w = (char*)d_ws;
  unsigned short* z2 = (unsigned short*)w; w += align256((size_t)NN * DD * 2);
  unsigned short* hb = (unsigned short*)w; w += align256((size_t)NN * DD * 2);
  int*   row_ptr  = (int*)w;   w += align256((size_t)(NN + 1) * 4);
  int*   counts   = (int*)w;   w += align256((size_t)NN * 4);
  int*   off      = (int*)w;   w += align256((size_t)NN * 4);
  int2*  csr      = (int2*)w;  w += align256((size_t)NE * 8);
  float* stats4   = (float*)w; w += align256((size_t)NL * 256 * 4);
  int*   bsums    = (int*)w;   w += align256(ST * 4);
  int*   boffs    = (int*)w;   w += align256(ST * 4);
  unsigned short* WTb = (unsigned short*)w; w += align256((size_t)8 * 16384 * 2);

  // weight prep (zeroes counts+stats) -> h2b (fused edge count) -> CSR build
  k_prep<<<512, 256, 0, stream>>>(W1, W2, WTb, counts, stats4);
  k_h2b<<<(NN * DD / 4 + 255) / 256, 256, 0, stream>>>(x, hb, ei, counts);
  k_scan_part<<<SB, ST, 0, stream>>>(counts, row_ptr, bsums);
  k_scan_bsum<<<1, ST, 0, stream>>>(bsums, boffs, row_ptr);
  k_scan_add<<<SB, ST, 0, stream>>>(boffs, row_ptr, off);
  k_fill<<<(NE + 255) / 256, 256, 0, stream>>>(ei, attr, off, csr);

  for (int l = 0; l < NL; l++) {
    float* st = stats4 + (size_t)l * 256;
    // z2(bf16) = AGG(hb) @ W1 + b1, fused aggregation + fused stats
    k_gemm<0><<<GB, 256, 0, stream>>>(nullptr, WTb + (size_t)l * 16384, b1 + l * DD,
                                      st, nullptr, nullptr, nullptr, nullptr, z2,
                                      hb, row_ptr, csr, We + l * DD, be + l * DD,
                                      eps + l);
    unsigned short* hbo = (l < NL - 1) ? hb : nullptr;
    if (l == 0)
      k_gemm<1><<<GB, 256, 0, stream>>>(z2, WTb + (size_t)(4 + l) * 16384, b2 + l * DD,
                                        st, gamma + l * DD, beta + l * DD,
                                        nullptr, out, hbo,
                                        nullptr, nullptr, nullptr, nullptr, nullptr,
                                        nullptr);
    else
      k_gemm<2><<<GB, 256, 0, stream>>>(z2, WTb + (size_t)(4 + l) * 16384, b2 + l * DD,
                                        st, gamma + l * DD, beta + l * DD,
                                        out, out, hbo,
                                        nullptr, nullptr, nullptr, nullptr, nullptr,
                                        nullptr);
  }
}

// Round 8
// 528.427 us; speedup vs baseline: 1.4157x; 1.2487x over previous
//
#include <hip/hip_runtime.h>

#define NN 100000
#define NE 600000
#define DD 128
#define NL 4
#define GB 512  // persistent GEMM grid: 2 blocks/CU x 256 CU

typedef __attribute__((ext_vector_type(8))) short short8;
typedef __attribute__((ext_vector_type(4))) float float4v;
typedef __attribute__((ext_vector_type(2))) float f2;

__device__ inline unsigned short f2bf(float f) {
  union { float f; unsigned u; } v; v.f = f;
  unsigned r = v.u + 0x7fff + ((v.u >> 16) & 1);  // round-to-nearest-even
  return (unsigned short)(r >> 16);
}
__device__ inline float bf2f(unsigned short u) {
  union { unsigned u; float f; } v; v.u = ((unsigned)u) << 16;
  return v.f;
}
__device__ inline f2 bfpair(unsigned u) {
  f2 r;
  r.x = __uint_as_float(u << 16);
  r.y = __uint_as_float(u & 0xffff0000u);
  return r;
}

// ---------------- one-time: W1/W2 -> bf16 transposed [n][k]; zero counts/stats ----
__global__ void k_prep(const float* __restrict__ W1, const float* __restrict__ W2,
                       unsigned short* __restrict__ WT, int* __restrict__ counts,
                       float* __restrict__ stats4) {
  int i = blockIdx.x * 256 + threadIdx.x;  // over 8*16384 = 131072
  if (i < NN) counts[i] = 0;
  if (i < NL * 256) stats4[i] = 0.f;
  if (i >= 8 * 16384) return;
  int m = i >> 14;
  int el = i & 16383;
  int k = el >> 7;
  int n = el & 127;
  const float* src = (m < 4) ? (W1 + (size_t)m * 16384) : (W2 + (size_t)(m - 4) * 16384);
  WT[(size_t)m * 16384 + n * 128 + k] = f2bf(src[k * 128 + n]);
}

// -------- setup: fp32 x -> bf16 mirror, fused edge counting (counts pre-zeroed) ----
__global__ void k_h2b(const float* __restrict__ src, unsigned short* __restrict__ dst,
                      const int* __restrict__ ei, int* __restrict__ counts) {
  int i = blockIdx.x * 256 + threadIdx.x;
  if (i < NE) atomicAdd(&counts[ei[NE + i]], 1);
  if (i >= NN * DD / 4) return;
  float4 v = ((const float4*)src)[i];
  ushort4 o;
  o.x = f2bf(v.x); o.y = f2bf(v.y); o.z = f2bf(v.z); o.w = f2bf(v.w);
  ((ushort4*)dst)[i] = o;
}

// ---------------- CSR build (once per call) ----------------
#define ST 256
#define SC 2
#define SB ((NN + ST * SC - 1) / (ST * SC))  // 196 blocks

__global__ void k_scan_part(const int* __restrict__ counts, int* __restrict__ row_ptr,
                            int* __restrict__ bsums) {
  __shared__ int s[ST];
  int b = blockIdx.x, t = threadIdx.x;
  int base = b * (ST * SC) + t * SC;
  int v0 = (base < NN) ? counts[base] : 0;
  int v1 = (base + 1 < NN) ? counts[base + 1] : 0;
  int tsum = v0 + v1;
  s[t] = tsum;
  __syncthreads();
  for (int d = 1; d < ST; d <<= 1) {
    int x = (t >= d) ? s[t - d] : 0;
    __syncthreads();
    s[t] += x;
    __syncthreads();
  }
  int excl = s[t] - tsum;
  if (base < NN) row_ptr[base] = excl;
  if (base + 1 < NN) row_ptr[base + 1] = excl + v0;
  if (t == ST - 1) bsums[b] = s[t];
}

__global__ void k_scan_bsum(const int* __restrict__ bsums, int* __restrict__ boffs,
                            int* __restrict__ row_ptr) {
  __shared__ int s[ST];
  int t = threadIdx.x;
  int v = (t < SB) ? bsums[t] : 0;
  s[t] = v;
  __syncthreads();
  for (int d = 1; d < ST; d <<= 1) {
    int x = (t >= d) ? s[t - d] : 0;
    __syncthreads();
    s[t] += x;
    __syncthreads();
  }
  if (t < SB) boffs[t] = s[t] - v;
  if (t == ST - 1) row_ptr[NN] = s[t];
}

// finalizes row_ptr and initializes off[] as ABSOLUTE write cursors (= row_ptr)
__global__ void k_scan_add(const int* __restrict__ boffs, int* __restrict__ row_ptr,
                           int* __restrict__ off) {
  int b = blockIdx.x, t = threadIdx.x;
  int base = b * (ST * SC) + t * SC;
  int o = boffs[b];
  if (base < NN) { int v = row_ptr[base] + o; row_ptr[base] = v; off[base] = v; }
  if (base + 1 < NN) { int v = row_ptr[base + 1] + o; row_ptr[base + 1] = v; off[base + 1] = v; }
}

// packed CSR record: .x = src node, .y = attr bits; absolute-cursor atomic
__global__ void k_fill(const int* __restrict__ ei, const float* __restrict__ attr,
                       int* __restrict__ off, int2* __restrict__ csr) {
  int e = blockIdx.x * 256 + threadIdx.x;
  if (e >= NE) return;
  int srcv = ei[e];
  int dstv = ei[NE + e];
  int idx = atomicAdd(&off[dstv], 1);
  csr[idx] = make_int2(srcv, __float_as_int(attr[e]));
}

// ------- aggregation: zb = bf16( (1+eps)*hb[n] + sum relu(hb[src]+attr*We+be) ) -------
// (R5 structure: 16 lanes/node, grid-stride, node-level prefetch, packed-pair math.)
__global__ __launch_bounds__(256) void k_agg(
    const unsigned short* __restrict__ hb,
    const int* __restrict__ row_ptr, const int2* __restrict__ csr,
    const float* __restrict__ We, const float* __restrict__ be,
    const float* __restrict__ epsp, unsigned short* __restrict__ zb) {
  const int tid0 = blockIdx.x * 256 + threadIdx.x;
  const int li = tid0 & 15;
  const int g0 = tid0 >> 4;
  const int NG = (gridDim.x * 256) >> 4;
  const int d0 = li * 8;

  const f2 we01 = *(const f2*)(We + d0);
  const f2 we23 = *(const f2*)(We + d0 + 2);
  const f2 we45 = *(const f2*)(We + d0 + 4);
  const f2 we67 = *(const f2*)(We + d0 + 6);
  const f2 be01 = *(const f2*)(be + d0);
  const f2 be23 = *(const f2*)(be + d0 + 2);
  const f2 be45 = *(const f2*)(be + d0 + 4);
  const f2 be67 = *(const f2*)(be + d0 + 6);
  const float ep = 1.f + epsp[0];
  f2 ep2; ep2.x = ep; ep2.y = ep;
  const f2 zero2 = {0.f, 0.f};

  int n = g0;
  if (n >= NN) return;
  int b = row_ptr[n], e = row_ptr[n + 1];
  int cnt = min(e - b, 16);
  int2 rec = (li < cnt) ? csr[b + li] : make_int2(0, 0);

  while (n < NN) {
    const int n2 = n + NG;
    int b2 = 0, e2 = 0;
    if (n2 < NN) { b2 = row_ptr[n2]; e2 = row_ptr[n2 + 1]; }  // prefetch next rowptr
    uint4 hs = *(const uint4*)(hb + (size_t)n * DD + d0);     // self term (early issue)

    const int myidx = rec.x;
    const float myatt = __int_as_float(rec.y);
    f2 a01 = zero2, a23 = zero2, a45 = zero2, a67 = zero2;

#define CONS8(hv, at)                                                         \
    do {                                                                      \
      f2 av; av.x = (at); av.y = (at);                                        \
      f2 sx;                                                                  \
      sx = bfpair((hv).x) + (av * we01 + be01);                               \
      a01 += __builtin_elementwise_max(sx, zero2);                            \
      sx = bfpair((hv).y) + (av * we23 + be23);                               \
      a23 += __builtin_elementwise_max(sx, zero2);                            \
      sx = bfpair((hv).z) + (av * we45 + be45);                               \
      a45 += __builtin_elementwise_max(sx, zero2);                            \
      sx = bfpair((hv).w) + (av * we67 + be67);                               \
      a67 += __builtin_elementwise_max(sx, zero2);                            \
    } while (0)

    int i = 0;
    for (; i + 4 <= cnt; i += 4) {
      int s0 = __shfl(myidx, i, 16);
      int s1 = __shfl(myidx, i + 1, 16);
      int s2 = __shfl(myidx, i + 2, 16);
      int s3 = __shfl(myidx, i + 3, 16);
      float a0 = __shfl(myatt, i, 16);
      float a1 = __shfl(myatt, i + 1, 16);
      float a2 = __shfl(myatt, i + 2, 16);
      float a3 = __shfl(myatt, i + 3, 16);
      uint4 hv0 = *(const uint4*)(hb + (size_t)s0 * DD + d0);
      uint4 hv1 = *(const uint4*)(hb + (size_t)s1 * DD + d0);
      uint4 hv2 = *(const uint4*)(hb + (size_t)s2 * DD + d0);
      uint4 hv3 = *(const uint4*)(hb + (size_t)s3 * DD + d0);
      CONS8(hv0, a0);
      CONS8(hv1, a1);
      CONS8(hv2, a2);
      CONS8(hv3, a3);
    }
    for (; i < cnt; i++) {
      int s = __shfl(myidx, i, 16);
      float a = __shfl(myatt, i, 16);
      uint4 hv = *(const uint4*)(hb + (size_t)s * DD + d0);
      CONS8(hv, a);
    }
    // degree > 16 tail (rare; correctness fallback)
    for (int j = b + 16; j < e; j++) {
      int2 r2 = csr[j];
      float a = __int_as_float(r2.y);
      uint4 hv = *(const uint4*)(hb + (size_t)r2.x * DD + d0);
      CONS8(hv, a);
    }
#undef CONS8

    // prefetch next node's CSR record (overlaps epilogue + next rowptr wait)
    int cnt2 = min(e2 - b2, 16);
    int2 rec2 = (n2 < NN && li < cnt2) ? csr[b2 + li] : make_int2(0, 0);

    f2 z01 = ep2 * bfpair(hs.x) + a01;
    f2 z23 = ep2 * bfpair(hs.y) + a23;
    f2 z45 = ep2 * bfpair(hs.z) + a45;
    f2 z67 = ep2 * bfpair(hs.w) + a67;
    uint4 o;
    o.x = (unsigned)f2bf(z01.x) | ((unsigned)f2bf(z01.y) << 16);
    o.y = (unsigned)f2bf(z23.x) | ((unsigned)f2bf(z23.y) << 16);
    o.z = (unsigned)f2bf(z45.x) | ((unsigned)f2bf(z45.y) << 16);
    o.w = (unsigned)f2bf(z67.x) | ((unsigned)f2bf(z67.y) << 16);
    *(uint4*)(zb + (size_t)n * DD + d0) = o;

    n = n2; b = b2; e = e2; cnt = cnt2; rec = rec2;
  }
}

// ---------------- persistent double-buffered MFMA bf16 GEMM (R5 algo, 8 waves) ----
// Same tile (64 rows), same LDS layout, same fragment indexing as R5 — but 512
// threads: wave w = (rowblk = w&3) x (colhalf = w>>2). Each wave: 16 MFMAs over a
// 16-row x 64-col quadrant-pair, 20 ds_read_b128/tile (vs 36), half the staging
// and epilogue per lane. LDS 69.6 KB caps 2 blocks/CU -> 16 waves/CU (2x R5 TLP).
// MODE 0: z2(bf16) = Xb@W + b, fused column stats (sum,sumsq) -> stats[256]
// MODE 1: Y = relu( relu(bn(Xb))@W + b );       Ybf = bf16(Y) if non-null
// MODE 2: Y = hprev + relu( relu(bn(Xb))@W + b ); same mirror (hprev==Y safe)
template <int MODE>
__global__ __launch_bounds__(512) void k_gemm(
    const unsigned short* __restrict__ Xb, const unsigned short* __restrict__ WT,
    const float* __restrict__ bias, float* __restrict__ stats,
    const float* __restrict__ gamma, const float* __restrict__ beta,
    const float* __restrict__ hprev, float* __restrict__ Yout,
    unsigned short* __restrict__ Ybf) {
  __shared__ unsigned short Wl[128 * 136];     // 34816 B
  __shared__ unsigned short Xl[2][64 * 136];   // 2 x 17408 B
  __shared__ float bns[256];                   // 1024 B -> total 70656 B, 2 blk/CU
  const int tid = threadIdx.x;
  const int G = gridDim.x;
  const int NT = (NN + 63) >> 6;  // 1563

  // stage W^T bf16 [n][k] -> LDS, once per block
  for (int i = tid; i < 2048; i += 512) {
    int rr = i >> 4, c = i & 15;
    *(uint4*)&Wl[rr * 136 + c * 8] = *(const uint4*)&WT[rr * 128 + c * 8];
  }

  const int lane = tid & 63;
  const int w = tid >> 6;        // 0..7
  const int m = lane & 15;
  const int quad = lane >> 4;
  const int rowblk = w & 3;      // which 16-row block of the 64-row tile
  const int colh = w >> 1 & 2;   // 0 or 2: colhalf*2 (ct base offset /16)... see below
  const int ctbase = (w >> 2) * 4;  // ct in [ctbase, ctbase+4): cols ctbase*16..+64

  // bias hoisted: 4 float4 per wave (its 64 columns)
  float4 b4[4];
#pragma unroll
  for (int c = 0; c < 4; c++)
    b4[c] = *(const float4*)&bias[(ctbase + c) * 16 + quad * 4];

  // staging mapping: 16B bf16 chunks; c8 = staging lane (0..15), rows rr16 + it*32
  const int c8 = tid & 15, rr16 = tid >> 4;  // rr16 in 0..31
  float scl[8], sfl[8];
  if (MODE >= 1) {
    if (tid < 128) {
      const float invN = 1.f / (float)NN;
      float mu = stats[tid] * invN;
      float var = fmaxf(stats[128 + tid] * invN - mu * mu, 0.f);
      float xx = var + 1e-5f;
      float r = rsqrtf(xx);
      r = r * (1.5f - 0.5f * xx * r * r);  // Newton step
      float scale = gamma[tid] * r;
      bns[tid] = scale;
      bns[128 + tid] = beta[tid] - mu * scale;
    }
    __syncthreads();
#pragma unroll
    for (int j = 0; j < 8; j++) {
      scl[j] = bns[c8 * 8 + j];
      sfl[j] = bns[128 + c8 * 8 + j];
    }
  }

  uint4 xu[2];  // prefetch regs (8 bf16 each)
  auto LOADR = [&](int t) {
    int r0 = t << 6;
#pragma unroll
    for (int it = 0; it < 2; it++) {
      int gr = r0 + rr16 + it * 32;
      xu[it] = (gr < NN) ? *(const uint4*)(Xb + (size_t)gr * DD + c8 * 8)
                         : make_uint4(0u, 0u, 0u, 0u);
    }
  };
  auto STORE_LDS = [&](int b) {
#pragma unroll
    for (int it = 0; it < 2; it++) {
      int row = rr16 + it * 32;
      uint4 u = xu[it];
      if (MODE >= 1) {
        unsigned p[4] = {u.x, u.y, u.z, u.w};
#pragma unroll
        for (int j = 0; j < 4; j++) {
          float lo = bf2f((unsigned short)(p[j] & 0xffffu));
          float hi = bf2f((unsigned short)(p[j] >> 16));
          lo = fmaxf(fmaf(lo, scl[2 * j], sfl[2 * j]), 0.f);
          hi = fmaxf(fmaf(hi, scl[2 * j + 1], sfl[2 * j + 1]), 0.f);
          p[j] = (unsigned)f2bf(lo) | ((unsigned)f2bf(hi) << 16);
        }
        u = make_uint4(p[0], p[1], p[2], p[3]);
      }
      *(uint4*)&Xl[b][row * 136 + c8 * 8] = u;
    }
  };

  float4v ssum[4], ssq[4];
  if (MODE == 0) {
#pragma unroll
    for (int c = 0; c < 4; c++) {
      ssum[c] = (float4v){0.f, 0.f, 0.f, 0.f};
      ssq[c] = (float4v){0.f, 0.f, 0.f, 0.f};
    }
  }

  const int t0 = blockIdx.x;
  LOADR(t0);
  STORE_LDS(0);
  if (t0 + G < NT) LOADR(t0 + G);
  __syncthreads();  // Xl[0] + Wl ready

  int buf = 0;
  for (int t = t0; t < NT; t += G) {
    const int nxt = t + G;
    if (nxt < NT) {
      STORE_LDS(buf ^ 1);                 // regs hold tile nxt (loaded last iter)
      if (nxt + G < NT) LOADR(nxt + G);   // prefetch tile nxt+G
    }

    float4v acc[4];
#pragma unroll
    for (int c = 0; c < 4; c++)
      acc[c] = (float4v){b4[c].x, b4[c].y, b4[c].z, b4[c].w};

    // A = W^T rows (this wave's 64 out cols), B = X rows (this wave's 16-row block)
    const unsigned short* Ap = &Wl[(ctbase * 16 + m) * 136 + quad * 8];
    const unsigned short* Bp = &Xl[buf][(rowblk * 16 + m) * 136 + quad * 8];
#pragma unroll
    for (int q = 0; q < 4; q++) {
      short8 bfrag = *(const short8*)(Bp + q * 32);
#pragma unroll
      for (int c = 0; c < 4; c++) {
        short8 afrag = *(const short8*)(Ap + c * 16 * 136 + q * 32);
        acc[c] = __builtin_amdgcn_mfma_f32_16x16x32_bf16(afrag, bfrag, acc[c], 0, 0, 0);
      }
    }

    // LDS-only fence; epilogue global stores stay in flight across tiles.
    asm volatile("s_waitcnt lgkmcnt(0)" ::: "memory");
    __builtin_amdgcn_s_barrier();

    const int r = (t << 6) + rowblk * 16 + m;  // this lane's output row
    if (r < NN) {
      const size_t rb = (size_t)r * DD;
#pragma unroll
      for (int c = 0; c < 4; c++) {
        float4v v = acc[c];
        const int col = (ctbase + c) * 16 + quad * 4;
        if (MODE == 0) {
          ssum[c] += v;
          ssq[c] += v * v;
          ushort4 o;
          o.x = f2bf(v[0]); o.y = f2bf(v[1]); o.z = f2bf(v[2]); o.w = f2bf(v[3]);
          *(ushort4*)&Ybf[rb + col] = o;
        } else {
          v[0] = fmaxf(v[0], 0.f); v[1] = fmaxf(v[1], 0.f);
          v[2] = fmaxf(v[2], 0.f); v[3] = fmaxf(v[3], 0.f);
          if (MODE == 2) {
            float4 hp = *(const float4*)&hprev[rb + col];
            v[0] += hp.x; v[1] += hp.y; v[2] += hp.z; v[3] += hp.w;
          }
          *(float4v*)&Yout[rb + col] = v;
          if (Ybf) {
            ushort4 o;
            o.x = f2bf(v[0]); o.y = f2bf(v[1]); o.z = f2bf(v[2]); o.w = f2bf(v[3]);
            *(ushort4*)&Ybf[rb + col] = o;
          }
        }
      }
    }
    buf ^= 1;
  }

  if (MODE == 0) {
    // per-wave reduce over the 16 m-lanes, partials to LDS scratch [8][64],
    // then 128 threads fold the 4 row-block waves per column half -> 256 atomics.
    float* sarr = (float*)Xl;    // [8][64]
    float* sqarr = sarr + 512;   // [8][64]
#pragma unroll
    for (int c = 0; c < 4; c++) {
      float4v s = ssum[c], s2 = ssq[c];
#pragma unroll
      for (int d = 1; d < 16; d <<= 1) {
#pragma unroll
        for (int j = 0; j < 4; j++) {
          s[j] += __shfl_xor(s[j], d);
          s2[j] += __shfl_xor(s2[j], d);
        }
      }
      if (m == 0) {
        *(float4v*)&sarr[w * 64 + c * 16 + quad * 4] = s;
        *(float4v*)&sqarr[w * 64 + c * 16 + quad * 4] = s2;
      }
    }
    __syncthreads();
    if (tid < 128) {
      const int ch = tid >> 6;   // column half: waves ch*4 .. ch*4+3 cover it
      const int cl = tid & 63;
      float s = 0.f, s2 = 0.f;
#pragma unroll
      for (int ww = 0; ww < 4; ww++) {
        s += sarr[(ch * 4 + ww) * 64 + cl];
        s2 += sqarr[(ch * 4 + ww) * 64 + cl];
      }
      atomicAdd(&stats[tid], s);
      atomicAdd(&stats[128 + tid], s2);
    }
  }
}

// ---------------- driver ----------------
static inline size_t align256(size_t x) { return (x + 255) & ~(size_t)255; }

extern "C" void kernel_launch(void* const* d_in, const int* in_sizes, int n_in,
                              void* d_out, int out_size, void* d_ws, size_t ws_size,
                              hipStream_t stream) {
  const float* x     = (const float*)d_in[0];
  const int*   ei    = (const int*)d_in[1];
  const float* attr  = (const float*)d_in[2];
  const float* We    = (const float*)d_in[3];
  const float* be    = (const float*)d_in[4];
  const float* eps   = (const float*)d_in[5];
  const float* W1    = (const float*)d_in[6];
  const float* b1    = (const float*)d_in[7];
  const float* gamma = (const float*)d_in[8];
  const float* beta  = (const float*)d_in[9];
  const float* W2    = (const float*)d_in[10];
  const float* b2    = (const float*)d_in[11];
  float* out = (float*)d_out;

  char* w = (char*)d_ws;
  unsigned short* z2 = (unsigned short*)w; w += align256((size_t)NN * DD * 2);
  unsigned short* hb = (unsigned short*)w; w += align256((size_t)NN * DD * 2);
  unsigned short* zb = (unsigned short*)w; w += align256((size_t)NN * DD * 2);
  int*   row_ptr  = (int*)w;   w += align256((size_t)(NN + 1) * 4);
  int*   counts   = (int*)w;   w += align256((size_t)NN * 4);
  int*   off      = (int*)w;   w += align256((size_t)NN * 4);
  int2*  csr      = (int2*)w;  w += align256((size_t)NE * 8);
  float* stats4   = (float*)w; w += align256((size_t)NL * 256 * 4);
  int*   bsums    = (int*)w;   w += align256(ST * 4);
  int*   boffs    = (int*)w;   w += align256(ST * 4);
  unsigned short* WTb = (unsigned short*)w; w += align256((size_t)8 * 16384 * 2);

  // weight prep (zeroes counts+stats) -> h2b (fused edge count) -> CSR build
  k_prep<<<512, 256, 0, stream>>>(W1, W2, WTb, counts, stats4);
  k_h2b<<<(NN * DD / 4 + 255) / 256, 256, 0, stream>>>(x, hb, ei, counts);
  k_scan_part<<<SB, ST, 0, stream>>>(counts, row_ptr, bsums);
  k_scan_bsum<<<1, ST, 0, stream>>>(bsums, boffs, row_ptr);
  k_scan_add<<<SB, ST, 0, stream>>>(boffs, row_ptr, off);
  k_fill<<<(NE + 255) / 256, 256, 0, stream>>>(ei, attr, off, csr);

  for (int l = 0; l < NL; l++) {
    float* st = stats4 + (size_t)l * 256;
    k_agg<<<1024, 256, 0, stream>>>(
        hb, row_ptr, csr, We + l * DD, be + l * DD, eps + l, zb);
    // z2(bf16) = zb @ W1 + b1, fused stats
    k_gemm<0><<<GB, 512, 0, stream>>>(zb, WTb + (size_t)l * 16384, b1 + l * DD,
                                      st, nullptr, nullptr, nullptr, nullptr, z2);
    unsigned short* hbo = (l < NL - 1) ? hb : nullptr;
    if (l == 0)
      k_gemm<1><<<GB, 512, 0, stream>>>(z2, WTb + (size_t)(4 + l) * 16384, b2 + l * DD,
                                        st, gamma + l * DD, beta + l * DD,
                                        nullptr, out, hbo);
    else
      k_gemm<2><<<GB, 512, 0, stream>>>(z2, WTb + (size_t)(4 + l) * 16384, b2 + l * DD,
                                        st, gamma + l * DD, beta + l * DD,
                                        out, out, hbo);
  }
}

// Round 9
// 523.927 us; speedup vs baseline: 1.4279x; 1.0086x over previous
//
#include <hip/hip_runtime.h>

#define NN 100000
#define NE 600000
#define DD 128
#define NL 4
#define GB 512  // persistent GEMM grid: 2 blocks/CU x 256 CU

typedef __attribute__((ext_vector_type(8))) short short8;
typedef __attribute__((ext_vector_type(4))) float float4v;
typedef __attribute__((ext_vector_type(2))) float f2;

__device__ inline unsigned short f2bf(float f) {
  union { float f; unsigned u; } v; v.f = f;
  unsigned r = v.u + 0x7fff + ((v.u >> 16) & 1);  // round-to-nearest-even
  return (unsigned short)(r >> 16);
}
__device__ inline float bf2f(unsigned short u) {
  union { unsigned u; float f; } v; v.u = ((unsigned)u) << 16;
  return v.f;
}
__device__ inline f2 bfpair(unsigned u) {
  f2 r;
  r.x = __uint_as_float(u << 16);
  r.y = __uint_as_float(u & 0xffff0000u);
  return r;
}

// ---------------- one-time: W1/W2 -> bf16 transposed [n][k]; zero counts/stats ----
__global__ void k_prep(const float* __restrict__ W1, const float* __restrict__ W2,
                       unsigned short* __restrict__ WT, int* __restrict__ counts,
                       float* __restrict__ stats4) {
  int i = blockIdx.x * 256 + threadIdx.x;  // over 8*16384 = 131072
  if (i < NN) counts[i] = 0;
  if (i < NL * 256) stats4[i] = 0.f;
  if (i >= 8 * 16384) return;
  int m = i >> 14;
  int el = i & 16383;
  int k = el >> 7;
  int n = el & 127;
  const float* src = (m < 4) ? (W1 + (size_t)m * 16384) : (W2 + (size_t)(m - 4) * 16384);
  WT[(size_t)m * 16384 + n * 128 + k] = f2bf(src[k * 128 + n]);
}

// -------- setup: fp32 x -> bf16 mirror, fused edge counting (counts pre-zeroed) ----
__global__ void k_h2b(const float* __restrict__ src, unsigned short* __restrict__ dst,
                      const int* __restrict__ ei, int* __restrict__ counts) {
  int i = blockIdx.x * 256 + threadIdx.x;
  if (i < NE) atomicAdd(&counts[ei[NE + i]], 1);
  if (i >= NN * DD / 4) return;
  float4 v = ((const float4*)src)[i];
  ushort4 o;
  o.x = f2bf(v.x); o.y = f2bf(v.y); o.z = f2bf(v.z); o.w = f2bf(v.w);
  ((ushort4*)dst)[i] = o;
}

// ---------------- CSR build (once per call) ----------------
#define ST 256
#define SC 2
#define SB ((NN + ST * SC - 1) / (ST * SC))  // 196 blocks

__global__ void k_scan_part(const int* __restrict__ counts, int* __restrict__ row_ptr,
                            int* __restrict__ bsums) {
  __shared__ int s[ST];
  int b = blockIdx.x, t = threadIdx.x;
  int base = b * (ST * SC) + t * SC;
  int v0 = (base < NN) ? counts[base] : 0;
  int v1 = (base + 1 < NN) ? counts[base + 1] : 0;
  int tsum = v0 + v1;
  s[t] = tsum;
  __syncthreads();
  for (int d = 1; d < ST; d <<= 1) {
    int x = (t >= d) ? s[t - d] : 0;
    __syncthreads();
    s[t] += x;
    __syncthreads();
  }
  int excl = s[t] - tsum;
  if (base < NN) row_ptr[base] = excl;
  if (base + 1 < NN) row_ptr[base + 1] = excl + v0;
  if (t == ST - 1) bsums[b] = s[t];
}

__global__ void k_scan_bsum(const int* __restrict__ bsums, int* __restrict__ boffs,
                            int* __restrict__ row_ptr) {
  __shared__ int s[ST];
  int t = threadIdx.x;
  int v = (t < SB) ? bsums[t] : 0;
  s[t] = v;
  __syncthreads();
  for (int d = 1; d < ST; d <<= 1) {
    int x = (t >= d) ? s[t - d] : 0;
    __syncthreads();
    s[t] += x;
    __syncthreads();
  }
  if (t < SB) boffs[t] = s[t] - v;
  if (t == ST - 1) row_ptr[NN] = s[t];
}

// finalizes row_ptr and initializes off[] as ABSOLUTE write cursors (= row_ptr)
__global__ void k_scan_add(const int* __restrict__ boffs, int* __restrict__ row_ptr,
                           int* __restrict__ off) {
  int b = blockIdx.x, t = threadIdx.x;
  int base = b * (ST * SC) + t * SC;
  int o = boffs[b];
  if (base < NN) { int v = row_ptr[base] + o; row_ptr[base] = v; off[base] = v; }
  if (base + 1 < NN) { int v = row_ptr[base + 1] + o; row_ptr[base + 1] = v; off[base + 1] = v; }
}

// packed CSR record: .x = src node, .y = attr bits; absolute-cursor atomic
__global__ void k_fill(const int* __restrict__ ei, const float* __restrict__ attr,
                       int* __restrict__ off, int2* __restrict__ csr) {
  int e = blockIdx.x * 256 + threadIdx.x;
  if (e >= NE) return;
  int srcv = ei[e];
  int dstv = ei[NE + e];
  int idx = atomicAdd(&off[dstv], 1);
  csr[idx] = make_int2(srcv, __float_as_int(attr[e]));
}

// ------- aggregation: zb = bf16( (1+eps)*hb[n] + sum relu(hb[src]+attr*We+be) ) -------
// 16 lanes/node, grid-stride. 8-deep predicated gather batches: all 8 loads of a
// batch are issued back-to-back (lanes beyond cnt hold rec=(0,0) -> harmless row-0
// loads, L2-resident), consume is guarded per edge. No serial tail for deg<=16.
#define CONS8(hv, at)                                                         \
  do {                                                                        \
    f2 av; av.x = (at); av.y = (at);                                          \
    f2 sx;                                                                    \
    sx = bfpair((hv).x) + (av * we01 + be01);                                 \
    a01 += __builtin_elementwise_max(sx, zero2);                              \
    sx = bfpair((hv).y) + (av * we23 + be23);                                 \
    a23 += __builtin_elementwise_max(sx, zero2);                              \
    sx = bfpair((hv).z) + (av * we45 + be45);                                 \
    a45 += __builtin_elementwise_max(sx, zero2);                              \
    sx = bfpair((hv).w) + (av * we67 + be67);                                 \
    a67 += __builtin_elementwise_max(sx, zero2);                              \
  } while (0)

#define LDROW(s) (*(const uint4*)(hb + (size_t)(s) * DD + d0))

__global__ __launch_bounds__(256) void k_agg(
    const unsigned short* __restrict__ hb,
    const int* __restrict__ row_ptr, const int2* __restrict__ csr,
    const float* __restrict__ We, const float* __restrict__ be,
    const float* __restrict__ epsp, unsigned short* __restrict__ zb) {
  const int tid0 = blockIdx.x * 256 + threadIdx.x;
  const int li = tid0 & 15;
  const int g0 = tid0 >> 4;
  const int NG = (gridDim.x * 256) >> 4;
  const int d0 = li * 8;

  const f2 we01 = *(const f2*)(We + d0);
  const f2 we23 = *(const f2*)(We + d0 + 2);
  const f2 we45 = *(const f2*)(We + d0 + 4);
  const f2 we67 = *(const f2*)(We + d0 + 6);
  const f2 be01 = *(const f2*)(be + d0);
  const f2 be23 = *(const f2*)(be + d0 + 2);
  const f2 be45 = *(const f2*)(be + d0 + 4);
  const f2 be67 = *(const f2*)(be + d0 + 6);
  const float ep = 1.f + epsp[0];
  f2 ep2; ep2.x = ep; ep2.y = ep;
  const f2 zero2 = {0.f, 0.f};

  for (int n = g0; n < NN; n += NG) {
    const int b = row_ptr[n], e = row_ptr[n + 1];
    const int deg = e - b;
    const int cnt = (deg < 16) ? deg : 16;
    int2 rec = (li < cnt) ? csr[b + li] : make_int2(0, 0);
    uint4 hs = LDROW(n);  // self term, issued early
    const int myidx = rec.x;
    const float myatt = __int_as_float(rec.y);
    f2 a01 = zero2, a23 = zero2, a45 = zero2, a67 = zero2;

    // ---- batch 0: edges 0..7, 8 gathers in flight ----
    {
      int s0 = __shfl(myidx, 0, 16), s1 = __shfl(myidx, 1, 16);
      int s2 = __shfl(myidx, 2, 16), s3 = __shfl(myidx, 3, 16);
      int s4 = __shfl(myidx, 4, 16), s5 = __shfl(myidx, 5, 16);
      int s6 = __shfl(myidx, 6, 16), s7 = __shfl(myidx, 7, 16);
      float t0 = __shfl(myatt, 0, 16), t1 = __shfl(myatt, 1, 16);
      float t2 = __shfl(myatt, 2, 16), t3 = __shfl(myatt, 3, 16);
      float t4 = __shfl(myatt, 4, 16), t5 = __shfl(myatt, 5, 16);
      float t6 = __shfl(myatt, 6, 16), t7 = __shfl(myatt, 7, 16);
      uint4 h0 = LDROW(s0), h1 = LDROW(s1), h2 = LDROW(s2), h3 = LDROW(s3);
      uint4 h4 = LDROW(s4), h5 = LDROW(s5), h6 = LDROW(s6), h7 = LDROW(s7);
      if (cnt > 0) CONS8(h0, t0);
      if (cnt > 1) CONS8(h1, t1);
      if (cnt > 2) CONS8(h2, t2);
      if (cnt > 3) CONS8(h3, t3);
      if (cnt > 4) CONS8(h4, t4);
      if (cnt > 5) CONS8(h5, t5);
      if (cnt > 6) CONS8(h6, t6);
      if (cnt > 7) CONS8(h7, t7);
    }
    if (deg > 8) {
      // ---- batch 1: edges 8..15 ----
      int s0 = __shfl(myidx, 8, 16), s1 = __shfl(myidx, 9, 16);
      int s2 = __shfl(myidx, 10, 16), s3 = __shfl(myidx, 11, 16);
      int s4 = __shfl(myidx, 12, 16), s5 = __shfl(myidx, 13, 16);
      int s6 = __shfl(myidx, 14, 16), s7 = __shfl(myidx, 15, 16);
      float t0 = __shfl(myatt, 8, 16), t1 = __shfl(myatt, 9, 16);
      float t2 = __shfl(myatt, 10, 16), t3 = __shfl(myatt, 11, 16);
      float t4 = __shfl(myatt, 12, 16), t5 = __shfl(myatt, 13, 16);
      float t6 = __shfl(myatt, 14, 16), t7 = __shfl(myatt, 15, 16);
      uint4 h0 = LDROW(s0), h1 = LDROW(s1), h2 = LDROW(s2), h3 = LDROW(s3);
      uint4 h4 = LDROW(s4), h5 = LDROW(s5), h6 = LDROW(s6), h7 = LDROW(s7);
      if (cnt > 8)  CONS8(h0, t0);
      if (cnt > 9)  CONS8(h1, t1);
      if (cnt > 10) CONS8(h2, t2);
      if (cnt > 11) CONS8(h3, t3);
      if (cnt > 12) CONS8(h4, t4);
      if (cnt > 13) CONS8(h5, t5);
      if (cnt > 14) CONS8(h6, t6);
      if (cnt > 15) CONS8(h7, t7);
      // degree > 16 tail (rare; correctness fallback)
      for (int j = b + 16; j < e; j++) {
        int2 r2 = csr[j];
        float a = __int_as_float(r2.y);
        uint4 hv = LDROW(r2.x);
        CONS8(hv, a);
      }
    }

    f2 z01 = ep2 * bfpair(hs.x) + a01;
    f2 z23 = ep2 * bfpair(hs.y) + a23;
    f2 z45 = ep2 * bfpair(hs.z) + a45;
    f2 z67 = ep2 * bfpair(hs.w) + a67;
    uint4 o;
    o.x = (unsigned)f2bf(z01.x) | ((unsigned)f2bf(z01.y) << 16);
    o.y = (unsigned)f2bf(z23.x) | ((unsigned)f2bf(z23.y) << 16);
    o.z = (unsigned)f2bf(z45.x) | ((unsigned)f2bf(z45.y) << 16);
    o.w = (unsigned)f2bf(z67.x) | ((unsigned)f2bf(z67.y) << 16);
    *(uint4*)(zb + (size_t)n * DD + d0) = o;
  }
}

// ---------------- persistent double-buffered MFMA bf16 GEMM (R8 structure) --------
// 512 threads: wave w = (rowblk = w&3) x (colhalf = w>>2); 16 MFMAs over a
// 16-row x 64-col quadrant-pair; LDS 69.6 KB -> 2 blocks/CU -> 16 waves/CU.
// MODE 0: z2(bf16) = Xb@W + b, fused column stats (sum,sumsq) -> stats[256]
// MODE 1: Y = relu( relu(bn(Xb))@W + b );       Ybf = bf16(Y) if non-null
// MODE 2: Y = hprev + relu( relu(bn(Xb))@W + b ); same mirror (hprev==Y safe)
template <int MODE>
__global__ __launch_bounds__(512) void k_gemm(
    const unsigned short* __restrict__ Xb, const unsigned short* __restrict__ WT,
    const float* __restrict__ bias, float* __restrict__ stats,
    const float* __restrict__ gamma, const float* __restrict__ beta,
    const float* __restrict__ hprev, float* __restrict__ Yout,
    unsigned short* __restrict__ Ybf) {
  __shared__ unsigned short Wl[128 * 136];     // 34816 B
  __shared__ unsigned short Xl[2][64 * 136];   // 2 x 17408 B
  __shared__ float bns[256];                   // 1024 B -> total 70656 B, 2 blk/CU
  const int tid = threadIdx.x;
  const int G = gridDim.x;
  const int NT = (NN + 63) >> 6;  // 1563

  // stage W^T bf16 [n][k] -> LDS, once per block
  for (int i = tid; i < 2048; i += 512) {
    int rr = i >> 4, c = i & 15;
    *(uint4*)&Wl[rr * 136 + c * 8] = *(const uint4*)&WT[rr * 128 + c * 8];
  }

  const int lane = tid & 63;
  const int w = tid >> 6;        // 0..7
  const int m = lane & 15;
  const int quad = lane >> 4;
  const int rowblk = w & 3;         // which 16-row block of the 64-row tile
  const int ctbase = (w >> 2) * 4;  // ct in [ctbase, ctbase+4): cols ctbase*16..+64

  // bias hoisted: 4 float4 per wave (its 64 columns)
  float4 b4[4];
#pragma unroll
  for (int c = 0; c < 4; c++)
    b4[c] = *(const float4*)&bias[(ctbase + c) * 16 + quad * 4];

  // staging mapping: 16B bf16 chunks; c8 = staging lane (0..15), rows rr16 + it*32
  const int c8 = tid & 15, rr16 = tid >> 4;  // rr16 in 0..31
  float scl[8], sfl[8];
  if (MODE >= 1) {
    if (tid < 128) {
      const float invN = 1.f / (float)NN;
      float mu = stats[tid] * invN;
      float var = fmaxf(stats[128 + tid] * invN - mu * mu, 0.f);
      float xx = var + 1e-5f;
      float r = rsqrtf(xx);
      r = r * (1.5f - 0.5f * xx * r * r);  // Newton step
      float scale = gamma[tid] * r;
      bns[tid] = scale;
      bns[128 + tid] = beta[tid] - mu * scale;
    }
    __syncthreads();
#pragma unroll
    for (int j = 0; j < 8; j++) {
      scl[j] = bns[c8 * 8 + j];
      sfl[j] = bns[128 + c8 * 8 + j];
    }
  }

  uint4 xu[2];  // prefetch regs (8 bf16 each)
  auto LOADR = [&](int t) {
    int r0 = t << 6;
#pragma unroll
    for (int it = 0; it < 2; it++) {
      int gr = r0 + rr16 + it * 32;
      xu[it] = (gr < NN) ? *(const uint4*)(Xb + (size_t)gr * DD + c8 * 8)
                         : make_uint4(0u, 0u, 0u, 0u);
    }
  };
  auto STORE_LDS = [&](int b) {
#pragma unroll
    for (int it = 0; it < 2; it++) {
      int row = rr16 + it * 32;
      uint4 u = xu[it];
      if (MODE >= 1) {
        unsigned p[4] = {u.x, u.y, u.z, u.w};
#pragma unroll
        for (int j = 0; j < 4; j++) {
          float lo = bf2f((unsigned short)(p[j] & 0xffffu));
          float hi = bf2f((unsigned short)(p[j] >> 16));
          lo = fmaxf(fmaf(lo, scl[2 * j], sfl[2 * j]), 0.f);
          hi = fmaxf(fmaf(hi, scl[2 * j + 1], sfl[2 * j + 1]), 0.f);
          p[j] = (unsigned)f2bf(lo) | ((unsigned)f2bf(hi) << 16);
        }
        u = make_uint4(p[0], p[1], p[2], p[3]);
      }
      *(uint4*)&Xl[b][row * 136 + c8 * 8] = u;
    }
  };

  float4v ssum[4], ssq[4];
  if (MODE == 0) {
#pragma unroll
    for (int c = 0; c < 4; c++) {
      ssum[c] = (float4v){0.f, 0.f, 0.f, 0.f};
      ssq[c] = (float4v){0.f, 0.f, 0.f, 0.f};
    }
  }

  const int t0 = blockIdx.x;
  LOADR(t0);
  STORE_LDS(0);
  if (t0 + G < NT) LOADR(t0 + G);
  __syncthreads();  // Xl[0] + Wl ready

  int buf = 0;
  for (int t = t0; t < NT; t += G) {
    const int nxt = t + G;
    if (nxt < NT) {
      STORE_LDS(buf ^ 1);                 // regs hold tile nxt (loaded last iter)
      if (nxt + G < NT) LOADR(nxt + G);   // prefetch tile nxt+G
    }

    float4v acc[4];
#pragma unroll
    for (int c = 0; c < 4; c++)
      acc[c] = (float4v){b4[c].x, b4[c].y, b4[c].z, b4[c].w};

    // A = W^T rows (this wave's 64 out cols), B = X rows (this wave's 16-row block)
    const unsigned short* Ap = &Wl[(ctbase * 16 + m) * 136 + quad * 8];
    const unsigned short* Bp = &Xl[buf][(rowblk * 16 + m) * 136 + quad * 8];
#pragma unroll
    for (int q = 0; q < 4; q++) {
      short8 bfrag = *(const short8*)(Bp + q * 32);
#pragma unroll
      for (int c = 0; c < 4; c++) {
        short8 afrag = *(const short8*)(Ap + c * 16 * 136 + q * 32);
        acc[c] = __builtin_amdgcn_mfma_f32_16x16x32_bf16(afrag, bfrag, acc[c], 0, 0, 0);
      }
    }

    // LDS-only fence; epilogue global stores stay in flight across tiles.
    asm volatile("s_waitcnt lgkmcnt(0)" ::: "memory");
    __builtin_amdgcn_s_barrier();

    const int r = (t << 6) + rowblk * 16 + m;  // this lane's output row
    if (r < NN) {
      const size_t rb = (size_t)r * DD;
#pragma unroll
      for (int c = 0; c < 4; c++) {
        float4v v = acc[c];
        const int col = (ctbase + c) * 16 + quad * 4;
        if (MODE == 0) {
          ssum[c] += v;
          ssq[c] += v * v;
          ushort4 o;
          o.x = f2bf(v[0]); o.y = f2bf(v[1]); o.z = f2bf(v[2]); o.w = f2bf(v[3]);
          *(ushort4*)&Ybf[rb + col] = o;
        } else {
          v[0] = fmaxf(v[0], 0.f); v[1] = fmaxf(v[1], 0.f);
          v[2] = fmaxf(v[2], 0.f); v[3] = fmaxf(v[3], 0.f);
          if (MODE == 2) {
            float4 hp = *(const float4*)&hprev[rb + col];
            v[0] += hp.x; v[1] += hp.y; v[2] += hp.z; v[3] += hp.w;
          }
          *(float4v*)&Yout[rb + col] = v;
          if (Ybf) {
            ushort4 o;
            o.x = f2bf(v[0]); o.y = f2bf(v[1]); o.z = f2bf(v[2]); o.w = f2bf(v[3]);
            *(ushort4*)&Ybf[rb + col] = o;
          }
        }
      }
    }
    buf ^= 1;
  }

  if (MODE == 0) {
    // per-wave reduce over the 16 m-lanes, partials to LDS scratch [8][64],
    // then 128 threads fold the 4 row-block waves per column half -> 256 atomics.
    float* sarr = (float*)Xl;    // [8][64]
    float* sqarr = sarr + 512;   // [8][64]
#pragma unroll
    for (int c = 0; c < 4; c++) {
      float4v s = ssum[c], s2 = ssq[c];
#pragma unroll
      for (int d = 1; d < 16; d <<= 1) {
#pragma unroll
        for (int j = 0; j < 4; j++) {
          s[j] += __shfl_xor(s[j], d);
          s2[j] += __shfl_xor(s2[j], d);
        }
      }
      if (m == 0) {
        *(float4v*)&sarr[w * 64 + c * 16 + quad * 4] = s;
        *(float4v*)&sqarr[w * 64 + c * 16 + quad * 4] = s2;
      }
    }
    __syncthreads();
    if (tid < 128) {
      const int ch = tid >> 6;   // column half: waves ch*4 .. ch*4+3 cover it
      const int cl = tid & 63;
      float s = 0.f, s2 = 0.f;
#pragma unroll
      for (int ww = 0; ww < 4; ww++) {
        s += sarr[(ch * 4 + ww) * 64 + cl];
        s2 += sqarr[(ch * 4 + ww) * 64 + cl];
      }
      atomicAdd(&stats[tid], s);
      atomicAdd(&stats[128 + tid], s2);
    }
  }
}

// ---------------- driver ----------------
static inline size_t align256(size_t x) { return (x + 255) & ~(size_t)255; }

extern "C" void kernel_launch(void* const* d_in, const int* in_sizes, int n_in,
                              void* d_out, int out_size, void* d_ws, size_t ws_size,
                              hipStream_t stream) {
  const float* x     = (const float*)d_in[0];
  const int*   ei    = (const int*)d_in[1];
  const float* attr  = (const float*)d_in[2];
  const float* We    = (const float*)d_in[3];
  const float* be    = (const float*)d_in[4];
  const float* eps   = (const float*)d_in[5];
  const float* W1    = (const float*)d_in[6];
  const float* b1    = (const float*)d_in[7];
  const float* gamma = (const float*)d_in[8];
  const float* beta  = (const float*)d_in[9];
  const float* W2    = (const float*)d_in[10];
  const float* b2    = (const float*)d_in[11];
  float* out = (float*)d_out;

  char* w = (char*)d_ws;
  unsigned short* z2 = (unsigned short*)w; w += align256((size_t)NN * DD * 2);
  unsigned short* hb = (unsigned short*)w; w += align256((size_t)NN * DD * 2);
  unsigned short* zb = (unsigned short*)w; w += align256((size_t)NN * DD * 2);
  int*   row_ptr  = (int*)w;   w += align256((size_t)(NN + 1) * 4);
  int*   counts   = (int*)w;   w += align256((size_t)NN * 4);
  int*   off      = (int*)w;   w += align256((size_t)NN * 4);
  int2*  csr      = (int2*)w;  w += align256((size_t)NE * 8);
  float* stats4   = (float*)w; w += align256((size_t)NL * 256 * 4);
  int*   bsums    = (int*)w;   w += align256(ST * 4);
  int*   boffs    = (int*)w;   w += align256(ST * 4);
  unsigned short* WTb = (unsigned short*)w; w += align256((size_t)8 * 16384 * 2);

  // weight prep (zeroes counts+stats) -> h2b (fused edge count) -> CSR build
  k_prep<<<512, 256, 0, stream>>>(W1, W2, WTb, counts, stats4);
  k_h2b<<<(NN * DD / 4 + 255) / 256, 256, 0, stream>>>(x, hb, ei, counts);
  k_scan_part<<<SB, ST, 0, stream>>>(counts, row_ptr, bsums);
  k_scan_bsum<<<1, ST, 0, stream>>>(bsums, boffs, row_ptr);
  k_scan_add<<<SB, ST, 0, stream>>>(boffs, row_ptr, off);
  k_fill<<<(NE + 255) / 256, 256, 0, stream>>>(ei, attr, off, csr);

  for (int l = 0; l < NL; l++) {
    float* st = stats4 + (size_t)l * 256;
    k_agg<<<2048, 256, 0, stream>>>(
        hb, row_ptr, csr, We + l * DD, be + l * DD, eps + l, zb);
    // z2(bf16) = zb @ W1 + b1, fused stats
    k_gemm<0><<<GB, 512, 0, stream>>>(zb, WTb + (size_t)l * 16384, b1 + l * DD,
                                      st, nullptr, nullptr, nullptr, nullptr, z2);
    unsigned short* hbo = (l < NL - 1) ? hb : nullptr;
    if (l == 0)
      k_gemm<1><<<GB, 512, 0, stream>>>(z2, WTb + (size_t)(4 + l) * 16384, b2 + l * DD,
                                        st, gamma + l * DD, beta + l * DD,
                                        nullptr, out, hbo);
    else
      k_gemm<2><<<GB, 512, 0, stream>>>(z2, WTb + (size_t)(4 + l) * 16384, b2 + l * DD,
                                        st, gamma + l * DD, beta + l * DD,
                                        out, out, hbo);
  }
}

// Round 10
// 522.646 us; speedup vs baseline: 1.4314x; 1.0025x over previous
//
#include <hip/hip_runtime.h>

#define NN 100000
#define NE 600000
#define DD 128
#define NL 4
#define GB 512   // persistent GEMM grid: 2 blocks/CU x 256 CU
#define BKS 9    // 512-node dst buckets
#define NBK ((NN + 511) >> 9)   // 196
#define CH 4096  // edges per k_bucket block

typedef __attribute__((ext_vector_type(8))) short short8;
typedef __attribute__((ext_vector_type(4))) float float4v;
typedef __attribute__((ext_vector_type(2))) float f2;

__device__ inline unsigned short f2bf(float f) {
  union { float f; unsigned u; } v; v.f = f;
  unsigned r = v.u + 0x7fff + ((v.u >> 16) & 1);  // round-to-nearest-even
  return (unsigned short)(r >> 16);
}
__device__ inline float bf2f(unsigned short u) {
  union { unsigned u; float f; } v; v.u = ((unsigned)u) << 16;
  return v.f;
}
__device__ inline f2 bfpair(unsigned u) {
  f2 r;
  r.x = __uint_as_float(u << 16);
  r.y = __uint_as_float(u & 0xffff0000u);
  return r;
}

// ---------------- one-time: W1/W2 -> bf16 transposed [n][k]; zero counts/stats ----
__global__ void k_prep(const float* __restrict__ W1, const float* __restrict__ W2,
                       unsigned short* __restrict__ WT, int* __restrict__ counts,
                       float* __restrict__ stats4) {
  int i = blockIdx.x * 256 + threadIdx.x;  // over 8*16384 = 131072
  if (i < NN) counts[i] = 0;
  if (i < NL * 256) stats4[i] = 0.f;
  if (i >= 8 * 16384) return;
  int m = i >> 14;
  int el = i & 16383;
  int k = el >> 7;
  int n = el & 127;
  const float* src = (m < 4) ? (W1 + (size_t)m * 16384) : (W2 + (size_t)(m - 4) * 16384);
  WT[(size_t)m * 16384 + n * 128 + k] = f2bf(src[k * 128 + n]);
}

// -------- setup: fp32 x -> bf16 mirror, fused edge counting (counts pre-zeroed) ----
__global__ void k_h2b(const float* __restrict__ src, unsigned short* __restrict__ dst,
                      const int* __restrict__ ei, int* __restrict__ counts) {
  int i = blockIdx.x * 256 + threadIdx.x;
  if (i < NE) atomicAdd(&counts[ei[NE + i]], 1);
  if (i >= NN * DD / 4) return;
  float4 v = ((const float4*)src)[i];
  ushort4 o;
  o.x = f2bf(v.x); o.y = f2bf(v.y); o.z = f2bf(v.z); o.w = f2bf(v.w);
  ((ushort4*)dst)[i] = o;
}

// ---------------- CSR build (once per call) ----------------
#define ST 256
#define SC 2
#define SB ((NN + ST * SC - 1) / (ST * SC))  // 196 blocks

__global__ void k_scan_part(const int* __restrict__ counts, int* __restrict__ row_ptr,
                            int* __restrict__ bsums) {
  __shared__ int s[ST];
  int b = blockIdx.x, t = threadIdx.x;
  int base = b * (ST * SC) + t * SC;
  int v0 = (base < NN) ? counts[base] : 0;
  int v1 = (base + 1 < NN) ? counts[base + 1] : 0;
  int tsum = v0 + v1;
  s[t] = tsum;
  __syncthreads();
  for (int d = 1; d < ST; d <<= 1) {
    int x = (t >= d) ? s[t - d] : 0;
    __syncthreads();
    s[t] += x;
    __syncthreads();
  }
  int excl = s[t] - tsum;
  if (base < NN) row_ptr[base] = excl;
  if (base + 1 < NN) row_ptr[base + 1] = excl + v0;
  if (t == ST - 1) bsums[b] = s[t];
}

__global__ void k_scan_bsum(const int* __restrict__ bsums, int* __restrict__ boffs,
                            int* __restrict__ row_ptr) {
  __shared__ int s[ST];
  int t = threadIdx.x;
  int v = (t < SB) ? bsums[t] : 0;
  s[t] = v;
  __syncthreads();
  for (int d = 1; d < ST; d <<= 1) {
    int x = (t >= d) ? s[t - d] : 0;
    __syncthreads();
    s[t] += x;
    __syncthreads();
  }
  if (t < SB) boffs[t] = s[t] - v;
  if (t == ST - 1) row_ptr[NN] = s[t];
}

// finalizes row_ptr and initializes per-bucket staging cursors scur[b] = row_ptr[512b]
__global__ void k_scan_add(const int* __restrict__ boffs, int* __restrict__ row_ptr,
                           int* __restrict__ scur) {
  int b = blockIdx.x, t = threadIdx.x;
  int base = b * (ST * SC) + t * SC;
  int o = boffs[b];
  if (base < NN) {
    int v = row_ptr[base] + o;
    row_ptr[base] = v;
    if ((base & 511) == 0) scur[base >> 9] = v;  // t==0: bucket base cursor
  }
  if (base + 1 < NN) row_ptr[base + 1] += o;
}

// ---- pass A: chunk edges -> group by 512-node dst-bucket in LDS -> staging ----
// staging record (8B): .x = src | (dst&511)<<17, .y = attr bits. Bucket regions of
// staging are aligned with csr regions (scur starts at row_ptr[512b]), so flushed
// runs (~21 edges avg) are contiguous & coalesced.
__global__ __launch_bounds__(256) void k_bucket(
    const int* __restrict__ ei, const float* __restrict__ attr,
    int* __restrict__ scur, int2* __restrict__ staging) {
  __shared__ int cnt[256], cnt2[256], base[256], gbase[256], s[256];
  __shared__ int lpk[CH];
  __shared__ int lat[CH];
  __shared__ unsigned char lbk[CH];
  const int t = threadIdx.x;
  const int c0 = blockIdx.x * CH;
  const int n = min(CH, NE - c0);
  cnt[t] = 0;
  cnt2[t] = 0;
  __syncthreads();
  // phase 1: per-bucket counts
  for (int k = t; k < n; k += 256) {
    int dst = ei[NE + c0 + k];
    atomicAdd(&cnt[dst >> BKS], 1);
  }
  __syncthreads();
  // exclusive prefix over buckets
  s[t] = cnt[t];
  __syncthreads();
  for (int d = 1; d < 256; d <<= 1) {
    int x = (t >= d) ? s[t - d] : 0;
    __syncthreads();
    s[t] += x;
    __syncthreads();
  }
  base[t] = s[t] - cnt[t];
  // reserve global staging space (one atomic per non-empty bucket per block)
  if (cnt[t] > 0) gbase[t] = atomicAdd(&scur[t], cnt[t]);
  __syncthreads();
  // phase 2: re-read edges (L2-hot), write grouped into LDS
  for (int k = t; k < n; k += 256) {
    int e = c0 + k;
    int src = ei[e];
    int dst = ei[NE + e];
    int b = dst >> BKS;
    int pos = base[b] + atomicAdd(&cnt2[b], 1);
    lpk[pos] = src | ((dst & 511) << 17);
    lat[pos] = __float_as_int(attr[e]);
    lbk[pos] = (unsigned char)b;
  }
  __syncthreads();
  // phase 3: flush grouped runs (coalesced within each bucket run)
  for (int k = t; k < n; k += 256) {
    int b = lbk[k];
    staging[gbase[b] + (k - base[b])] = make_int2(lpk[k], lat[k]);
  }
}

// ---- pass B: one block per bucket; LDS node cursors; scatter confined to the ----
// bucket's ~24KB csr region (single XCD L2 -> full-line writebacks).
__global__ __launch_bounds__(256) void k_place(
    const int* __restrict__ row_ptr, const int2* __restrict__ staging,
    int2* __restrict__ csr) {
  __shared__ int cur[512];
  const int b = blockIdx.x;
  const int n0 = b << BKS;
  const int nb = min(512, NN - n0);
  const int t = threadIdx.x;
  for (int j = t; j < nb; j += 256) cur[j] = row_ptr[n0 + j];
  __syncthreads();
  const int s0 = row_ptr[n0];
  const int s1 = row_ptr[n0 + nb];
  for (int i = s0 + t; i < s1; i += 256) {
    int2 r = staging[i];
    int j = ((unsigned)r.x) >> 17;
    int src = r.x & 0x1FFFF;
    int slot = atomicAdd(&cur[j], 1);
    csr[slot] = make_int2(src, r.y);
  }
}

// ------- aggregation: zb = bf16( (1+eps)*hb[n] + sum relu(hb[src]+attr*We+be) ) -------
// 16 lanes/node, grid-stride. 8-deep predicated gather batches.
#define CONS8(hv, at)                                                         \
  do {                                                                        \
    f2 av; av.x = (at); av.y = (at);                                          \
    f2 sx;                                                                    \
    sx = bfpair((hv).x) + (av * we01 + be01);                                 \
    a01 += __builtin_elementwise_max(sx, zero2);                              \
    sx = bfpair((hv).y) + (av * we23 + be23);                                 \
    a23 += __builtin_elementwise_max(sx, zero2);                              \
    sx = bfpair((hv).z) + (av * we45 + be45);                                 \
    a45 += __builtin_elementwise_max(sx, zero2);                              \
    sx = bfpair((hv).w) + (av * we67 + be67);                                 \
    a67 += __builtin_elementwise_max(sx, zero2);                              \
  } while (0)

#define LDROW(s) (*(const uint4*)(hb + (size_t)(s) * DD + d0))

__global__ __launch_bounds__(256) void k_agg(
    const unsigned short* __restrict__ hb,
    const int* __restrict__ row_ptr, const int2* __restrict__ csr,
    const float* __restrict__ We, const float* __restrict__ be,
    const float* __restrict__ epsp, unsigned short* __restrict__ zb) {
  const int tid0 = blockIdx.x * 256 + threadIdx.x;
  const int li = tid0 & 15;
  const int g0 = tid0 >> 4;
  const int NG = (gridDim.x * 256) >> 4;
  const int d0 = li * 8;

  const f2 we01 = *(const f2*)(We + d0);
  const f2 we23 = *(const f2*)(We + d0 + 2);
  const f2 we45 = *(const f2*)(We + d0 + 4);
  const f2 we67 = *(const f2*)(We + d0 + 6);
  const f2 be01 = *(const f2*)(be + d0);
  const f2 be23 = *(const f2*)(be + d0 + 2);
  const f2 be45 = *(const f2*)(be + d0 + 4);
  const f2 be67 = *(const f2*)(be + d0 + 6);
  const float ep = 1.f + epsp[0];
  f2 ep2; ep2.x = ep; ep2.y = ep;
  const f2 zero2 = {0.f, 0.f};

  for (int n = g0; n < NN; n += NG) {
    const int b = row_ptr[n], e = row_ptr[n + 1];
    const int deg = e - b;
    const int cnt = (deg < 16) ? deg : 16;
    int2 rec = (li < cnt) ? csr[b + li] : make_int2(0, 0);
    uint4 hs = LDROW(n);  // self term, issued early
    const int myidx = rec.x;
    const float myatt = __int_as_float(rec.y);
    f2 a01 = zero2, a23 = zero2, a45 = zero2, a67 = zero2;

    // ---- batch 0: edges 0..7, 8 gathers in flight ----
    {
      int s0 = __shfl(myidx, 0, 16), s1 = __shfl(myidx, 1, 16);
      int s2 = __shfl(myidx, 2, 16), s3 = __shfl(myidx, 3, 16);
      int s4 = __shfl(myidx, 4, 16), s5 = __shfl(myidx, 5, 16);
      int s6 = __shfl(myidx, 6, 16), s7 = __shfl(myidx, 7, 16);
      float t0 = __shfl(myatt, 0, 16), t1 = __shfl(myatt, 1, 16);
      float t2 = __shfl(myatt, 2, 16), t3 = __shfl(myatt, 3, 16);
      float t4 = __shfl(myatt, 4, 16), t5 = __shfl(myatt, 5, 16);
      float t6 = __shfl(myatt, 6, 16), t7 = __shfl(myatt, 7, 16);
      uint4 h0 = LDROW(s0), h1 = LDROW(s1), h2 = LDROW(s2), h3 = LDROW(s3);
      uint4 h4 = LDROW(s4), h5 = LDROW(s5), h6 = LDROW(s6), h7 = LDROW(s7);
      if (cnt > 0) CONS8(h0, t0);
      if (cnt > 1) CONS8(h1, t1);
      if (cnt > 2) CONS8(h2, t2);
      if (cnt > 3) CONS8(h3, t3);
      if (cnt > 4) CONS8(h4, t4);
      if (cnt > 5) CONS8(h5, t5);
      if (cnt > 6) CONS8(h6, t6);
      if (cnt > 7) CONS8(h7, t7);
    }
    if (deg > 8) {
      // ---- batch 1: edges 8..15 ----
      int s0 = __shfl(myidx, 8, 16), s1 = __shfl(myidx, 9, 16);
      int s2 = __shfl(myidx, 10, 16), s3 = __shfl(myidx, 11, 16);
      int s4 = __shfl(myidx, 12, 16), s5 = __shfl(myidx, 13, 16);
      int s6 = __shfl(myidx, 14, 16), s7 = __shfl(myidx, 15, 16);
      float t0 = __shfl(myatt, 8, 16), t1 = __shfl(myatt, 9, 16);
      float t2 = __shfl(myatt, 10, 16), t3 = __shfl(myatt, 11, 16);
      float t4 = __shfl(myatt, 12, 16), t5 = __shfl(myatt, 13, 16);
      float t6 = __shfl(myatt, 14, 16), t7 = __shfl(myatt, 15, 16);
      uint4 h0 = LDROW(s0), h1 = LDROW(s1), h2 = LDROW(s2), h3 = LDROW(s3);
      uint4 h4 = LDROW(s4), h5 = LDROW(s5), h6 = LDROW(s6), h7 = LDROW(s7);
      if (cnt > 8)  CONS8(h0, t0);
      if (cnt > 9)  CONS8(h1, t1);
      if (cnt > 10) CONS8(h2, t2);
      if (cnt > 11) CONS8(h3, t3);
      if (cnt > 12) CONS8(h4, t4);
      if (cnt > 13) CONS8(h5, t5);
      if (cnt > 14) CONS8(h6, t6);
      if (cnt > 15) CONS8(h7, t7);
      // degree > 16 tail (rare; correctness fallback)
      for (int j = b + 16; j < e; j++) {
        int2 r2 = csr[j];
        float a = __int_as_float(r2.y);
        uint4 hv = LDROW(r2.x);
        CONS8(hv, a);
      }
    }

    f2 z01 = ep2 * bfpair(hs.x) + a01;
    f2 z23 = ep2 * bfpair(hs.y) + a23;
    f2 z45 = ep2 * bfpair(hs.z) + a45;
    f2 z67 = ep2 * bfpair(hs.w) + a67;
    uint4 o;
    o.x = (unsigned)f2bf(z01.x) | ((unsigned)f2bf(z01.y) << 16);
    o.y = (unsigned)f2bf(z23.x) | ((unsigned)f2bf(z23.y) << 16);
    o.z = (unsigned)f2bf(z45.x) | ((unsigned)f2bf(z45.y) << 16);
    o.w = (unsigned)f2bf(z67.x) | ((unsigned)f2bf(z67.y) << 16);
    *(uint4*)(zb + (size_t)n * DD + d0) = o;
  }
}

// ---------------- persistent double-buffered MFMA bf16 GEMM (R8 structure) --------
// 512 threads: wave w = (rowblk = w&3) x (colhalf = w>>2); 16 MFMAs over a
// 16-row x 64-col quadrant-pair; LDS 69.6 KB -> 2 blocks/CU -> 16 waves/CU.
// MODE 0: z2(bf16) = Xb@W + b, fused column stats (sum,sumsq) -> stats[256]
// MODE 1: Y = relu( relu(bn(Xb))@W + b );       Ybf = bf16(Y) if non-null
// MODE 2: Y = hprev + relu( relu(bn(Xb))@W + b ); same mirror (hprev==Y safe)
template <int MODE>
__global__ __launch_bounds__(512) void k_gemm(
    const unsigned short* __restrict__ Xb, const unsigned short* __restrict__ WT,
    const float* __restrict__ bias, float* __restrict__ stats,
    const float* __restrict__ gamma, const float* __restrict__ beta,
    const float* __restrict__ hprev, float* __restrict__ Yout,
    unsigned short* __restrict__ Ybf) {
  __shared__ unsigned short Wl[128 * 136];     // 34816 B
  __shared__ unsigned short Xl[2][64 * 136];   // 2 x 17408 B
  __shared__ float bns[256];                   // 1024 B -> total 70656 B, 2 blk/CU
  const int tid = threadIdx.x;
  const int G = gridDim.x;
  const int NT = (NN + 63) >> 6;  // 1563

  // stage W^T bf16 [n][k] -> LDS, once per block
  for (int i = tid; i < 2048; i += 512) {
    int rr = i >> 4, c = i & 15;
    *(uint4*)&Wl[rr * 136 + c * 8] = *(const uint4*)&WT[rr * 128 + c * 8];
  }

  const int lane = tid & 63;
  const int w = tid >> 6;        // 0..7
  const int m = lane & 15;
  const int quad = lane >> 4;
  const int rowblk = w & 3;         // which 16-row block of the 64-row tile
  const int ctbase = (w >> 2) * 4;  // ct in [ctbase, ctbase+4): cols ctbase*16..+64

  // bias hoisted: 4 float4 per wave (its 64 columns)
  float4 b4[4];
#pragma unroll
  for (int c = 0; c < 4; c++)
    b4[c] = *(const float4*)&bias[(ctbase + c) * 16 + quad * 4];

  // staging mapping: 16B bf16 chunks; c8 = staging lane (0..15), rows rr16 + it*32
  const int c8 = tid & 15, rr16 = tid >> 4;  // rr16 in 0..31
  float scl[8], sfl[8];
  if (MODE >= 1) {
    if (tid < 128) {
      const float invN = 1.f / (float)NN;
      float mu = stats[tid] * invN;
      float var = fmaxf(stats[128 + tid] * invN - mu * mu, 0.f);
      float xx = var + 1e-5f;
      float r = rsqrtf(xx);
      r = r * (1.5f - 0.5f * xx * r * r);  // Newton step
      float scale = gamma[tid] * r;
      bns[tid] = scale;
      bns[128 + tid] = beta[tid] - mu * scale;
    }
    __syncthreads();
#pragma unroll
    for (int j = 0; j < 8; j++) {
      scl[j] = bns[c8 * 8 + j];
      sfl[j] = bns[128 + c8 * 8 + j];
    }
  }

  uint4 xu[2];  // prefetch regs (8 bf16 each)
  auto LOADR = [&](int t) {
    int r0 = t << 6;
#pragma unroll
    for (int it = 0; it < 2; it++) {
      int gr = r0 + rr16 + it * 32;
      xu[it] = (gr < NN) ? *(const uint4*)(Xb + (size_t)gr * DD + c8 * 8)
                         : make_uint4(0u, 0u, 0u, 0u);
    }
  };
  auto STORE_LDS = [&](int b) {
#pragma unroll
    for (int it = 0; it < 2; it++) {
      int row = rr16 + it * 32;
      uint4 u = xu[it];
      if (MODE >= 1) {
        unsigned p[4] = {u.x, u.y, u.z, u.w};
#pragma unroll
        for (int j = 0; j < 4; j++) {
          float lo = bf2f((unsigned short)(p[j] & 0xffffu));
          float hi = bf2f((unsigned short)(p[j] >> 16));
          lo = fmaxf(fmaf(lo, scl[2 * j], sfl[2 * j]), 0.f);
          hi = fmaxf(fmaf(hi, scl[2 * j + 1], sfl[2 * j + 1]), 0.f);
          p[j] = (unsigned)f2bf(lo) | ((unsigned)f2bf(hi) << 16);
        }
        u = make_uint4(p[0], p[1], p[2], p[3]);
      }
      *(uint4*)&Xl[b][row * 136 + c8 * 8] = u;
    }
  };

  float4v ssum[4], ssq[4];
  if (MODE == 0) {
#pragma unroll
    for (int c = 0; c < 4; c++) {
      ssum[c] = (float4v){0.f, 0.f, 0.f, 0.f};
      ssq[c] = (float4v){0.f, 0.f, 0.f, 0.f};
    }
  }

  const int t0 = blockIdx.x;
  LOADR(t0);
  STORE_LDS(0);
  if (t0 + G < NT) LOADR(t0 + G);
  __syncthreads();  // Xl[0] + Wl ready

  int buf = 0;
  for (int t = t0; t < NT; t += G) {
    const int nxt = t + G;
    if (nxt < NT) {
      STORE_LDS(buf ^ 1);                 // regs hold tile nxt (loaded last iter)
      if (nxt + G < NT) LOADR(nxt + G);   // prefetch tile nxt+G
    }

    float4v acc[4];
#pragma unroll
    for (int c = 0; c < 4; c++)
      acc[c] = (float4v){b4[c].x, b4[c].y, b4[c].z, b4[c].w};

    // A = W^T rows (this wave's 64 out cols), B = X rows (this wave's 16-row block)
    const unsigned short* Ap = &Wl[(ctbase * 16 + m) * 136 + quad * 8];
    const unsigned short* Bp = &Xl[buf][(rowblk * 16 + m) * 136 + quad * 8];
#pragma unroll
    for (int q = 0; q < 4; q++) {
      short8 bfrag = *(const short8*)(Bp + q * 32);
#pragma unroll
      for (int c = 0; c < 4; c++) {
        short8 afrag = *(const short8*)(Ap + c * 16 * 136 + q * 32);
        acc[c] = __builtin_amdgcn_mfma_f32_16x16x32_bf16(afrag, bfrag, acc[c], 0, 0, 0);
      }
    }

    // LDS-only fence; epilogue global stores stay in flight across tiles.
    asm volatile("s_waitcnt lgkmcnt(0)" ::: "memory");
    __builtin_amdgcn_s_barrier();

    const int r = (t << 6) + rowblk * 16 + m;  // this lane's output row
    if (r < NN) {
      const size_t rb = (size_t)r * DD;
#pragma unroll
      for (int c = 0; c < 4; c++) {
        float4v v = acc[c];
        const int col = (ctbase + c) * 16 + quad * 4;
        if (MODE == 0) {
          ssum[c] += v;
          ssq[c] += v * v;
          ushort4 o;
          o.x = f2bf(v[0]); o.y = f2bf(v[1]); o.z = f2bf(v[2]); o.w = f2bf(v[3]);
          *(ushort4*)&Ybf[rb + col] = o;
        } else {
          v[0] = fmaxf(v[0], 0.f); v[1] = fmaxf(v[1], 0.f);
          v[2] = fmaxf(v[2], 0.f); v[3] = fmaxf(v[3], 0.f);
          if (MODE == 2) {
            float4 hp = *(const float4*)&hprev[rb + col];
            v[0] += hp.x; v[1] += hp.y; v[2] += hp.z; v[3] += hp.w;
          }
          *(float4v*)&Yout[rb + col] = v;
          if (Ybf) {
            ushort4 o;
            o.x = f2bf(v[0]); o.y = f2bf(v[1]); o.z = f2bf(v[2]); o.w = f2bf(v[3]);
            *(ushort4*)&Ybf[rb + col] = o;
          }
        }
      }
    }
    buf ^= 1;
  }

  if (MODE == 0) {
    // per-wave reduce over the 16 m-lanes, partials to LDS scratch [8][64],
    // then 128 threads fold the 4 row-block waves per column half -> 256 atomics.
    float* sarr = (float*)Xl;    // [8][64]
    float* sqarr = sarr + 512;   // [8][64]
#pragma unroll
    for (int c = 0; c < 4; c++) {
      float4v s = ssum[c], s2 = ssq[c];
#pragma unroll
      for (int d = 1; d < 16; d <<= 1) {
#pragma unroll
        for (int j = 0; j < 4; j++) {
          s[j] += __shfl_xor(s[j], d);
          s2[j] += __shfl_xor(s2[j], d);
        }
      }
      if (m == 0) {
        *(float4v*)&sarr[w * 64 + c * 16 + quad * 4] = s;
        *(float4v*)&sqarr[w * 64 + c * 16 + quad * 4] = s2;
      }
    }
    __syncthreads();
    if (tid < 128) {
      const int ch = tid >> 6;   // column half: waves ch*4 .. ch*4+3 cover it
      const int cl = tid & 63;
      float s = 0.f, s2 = 0.f;
#pragma unroll
      for (int ww = 0; ww < 4; ww++) {
        s += sarr[(ch * 4 + ww) * 64 + cl];
        s2 += sqarr[(ch * 4 + ww) * 64 + cl];
      }
      atomicAdd(&stats[tid], s);
      atomicAdd(&stats[128 + tid], s2);
    }
  }
}

// ---------------- driver ----------------
static inline size_t align256(size_t x) { return (x + 255) & ~(size_t)255; }

extern "C" void kernel_launch(void* const* d_in, const int* in_sizes, int n_in,
                              void* d_out, int out_size, void* d_ws, size_t ws_size,
                              hipStream_t stream) {
  const float* x     = (const float*)d_in[0];
  const int*   ei    = (const int*)d_in[1];
  const float* attr  = (const float*)d_in[2];
  const float* We    = (const float*)d_in[3];
  const float* be    = (const float*)d_in[4];
  const float* eps   = (const float*)d_in[5];
  const float* W1    = (const float*)d_in[6];
  const float* b1    = (const float*)d_in[7];
  const float* gamma = (const float*)d_in[8];
  const float* beta  = (const float*)d_in[9];
  const float* W2    = (const float*)d_in[10];
  const float* b2    = (const float*)d_in[11];
  float* out = (float*)d_out;

  char* w = (char*)d_ws;
  unsigned short* z2 = (unsigned short*)w; w += align256((size_t)NN * DD * 2);
  unsigned short* hb = (unsigned short*)w; w += align256((size_t)NN * DD * 2);
  unsigned short* zb = (unsigned short*)w; w += align256((size_t)NN * DD * 2);
  int*   row_ptr  = (int*)w;   w += align256((size_t)(NN + 1) * 4);
  int*   counts   = (int*)w;   w += align256((size_t)NN * 4);
  int*   scur     = (int*)w;   w += align256(256 * 4);
  int2*  csr      = (int2*)w;  w += align256((size_t)NE * 8);
  int2*  staging  = (int2*)w;  w += align256((size_t)NE * 8);
  float* stats4   = (float*)w; w += align256((size_t)NL * 256 * 4);
  int*   bsums    = (int*)w;   w += align256(ST * 4);
  int*   boffs    = (int*)w;   w += align256(ST * 4);
  unsigned short* WTb = (unsigned short*)w; w += align256((size_t)8 * 16384 * 2);

  // weight prep (zeroes counts+stats) -> h2b (fused edge count) -> CSR build
  k_prep<<<512, 256, 0, stream>>>(W1, W2, WTb, counts, stats4);
  k_h2b<<<(NN * DD / 4 + 255) / 256, 256, 0, stream>>>(x, hb, ei, counts);
  k_scan_part<<<SB, ST, 0, stream>>>(counts, row_ptr, bsums);
  k_scan_bsum<<<1, ST, 0, stream>>>(bsums, boffs, row_ptr);
  k_scan_add<<<SB, ST, 0, stream>>>(boffs, row_ptr, scur);
  k_bucket<<<(NE + CH - 1) / CH, 256, 0, stream>>>(ei, attr, scur, staging);
  k_place<<<NBK, 256, 0, stream>>>(row_ptr, staging, csr);

  for (int l = 0; l < NL; l++) {
    float* st = stats4 + (size_t)l * 256;
    k_agg<<<2048, 256, 0, stream>>>(
        hb, row_ptr, csr, We + l * DD, be + l * DD, eps + l, zb);
    // z2(bf16) = zb @ W1 + b1, fused stats
    k_gemm<0><<<GB, 512, 0, stream>>>(zb, WTb + (size_t)l * 16384, b1 + l * DD,
                                      st, nullptr, nullptr, nullptr, nullptr, z2);
    unsigned short* hbo = (l < NL - 1) ? hb : nullptr;
    if (l == 0)
      k_gemm<1><<<GB, 512, 0, stream>>>(z2, WTb + (size_t)(4 + l) * 16384, b2 + l * DD,
                                        st, gamma + l * DD, beta + l * DD,
                                        nullptr, out, hbo);
    else
      k_gemm<2><<<GB, 512, 0, stream>>>(z2, WTb + (size_t)(4 + l) * 16384, b2 + l * DD,
                                        st, gamma + l * DD, beta + l * DD,
                                        out, out, hbo);
  }
}

// Round 12
// 514.403 us; speedup vs baseline: 1.4543x; 1.0160x over previous
//
#include <hip/hip_runtime.h>

#define NN 100000
#define NE 600000
#define DD 128
#define NL 4
#define GB 512   // persistent GEMM grid: 2 blocks/CU x 256 CU; <=4 tiles/block
#define BKS 9    // 512-node dst buckets
#define NBK ((NN + 511) >> 9)   // 196
#define CH 4096  // edges per k_bucket block

typedef __attribute__((ext_vector_type(8))) short short8;
typedef __attribute__((ext_vector_type(4))) float float4v;
typedef __attribute__((ext_vector_type(2))) float f2;

__device__ inline unsigned short f2bf(float f) {
  union { float f; unsigned u; } v; v.f = f;
  unsigned r = v.u + 0x7fff + ((v.u >> 16) & 1);  // round-to-nearest-even
  return (unsigned short)(r >> 16);
}
__device__ inline float bf2f(unsigned short u) {
  union { unsigned u; float f; } v; v.u = ((unsigned)u) << 16;
  return v.f;
}
__device__ inline f2 bfpair(unsigned u) {
  f2 r;
  r.x = __uint_as_float(u << 16);
  r.y = __uint_as_float(u & 0xffff0000u);
  return r;
}

// ---------------- one-time: W1/W2 -> bf16 transposed [n][k]; zero counts/stats ----
__global__ void k_prep(const float* __restrict__ W1, const float* __restrict__ W2,
                       unsigned short* __restrict__ WT, int* __restrict__ counts,
                       float* __restrict__ stats4) {
  int i = blockIdx.x * 256 + threadIdx.x;  // over 8*16384 = 131072
  if (i < NN) counts[i] = 0;
  if (i < NL * 256) stats4[i] = 0.f;
  if (i >= 8 * 16384) return;
  int m = i >> 14;
  int el = i & 16383;
  int k = el >> 7;
  int n = el & 127;
  const float* src = (m < 4) ? (W1 + (size_t)m * 16384) : (W2 + (size_t)(m - 4) * 16384);
  WT[(size_t)m * 16384 + n * 128 + k] = f2bf(src[k * 128 + n]);
}

// -------- setup: fp32 x -> bf16 mirror, fused edge counting (counts pre-zeroed) ----
__global__ void k_h2b(const float* __restrict__ src, unsigned short* __restrict__ dst,
                      const int* __restrict__ ei, int* __restrict__ counts) {
  int i = blockIdx.x * 256 + threadIdx.x;
  if (i < NE) atomicAdd(&counts[ei[NE + i]], 1);
  if (i >= NN * DD / 4) return;
  float4 v = ((const float4*)src)[i];
  ushort4 o;
  o.x = f2bf(v.x); o.y = f2bf(v.y); o.z = f2bf(v.z); o.w = f2bf(v.w);
  ((ushort4*)dst)[i] = o;
}

// ---------------- CSR build (once per call) ----------------
#define ST 256
#define SC 2
#define SB ((NN + ST * SC - 1) / (ST * SC))  // 196 blocks

__global__ void k_scan_part(const int* __restrict__ counts, int* __restrict__ row_ptr,
                            int* __restrict__ bsums) {
  __shared__ int s[ST];
  int b = blockIdx.x, t = threadIdx.x;
  int base = b * (ST * SC) + t * SC;
  int v0 = (base < NN) ? counts[base] : 0;
  int v1 = (base + 1 < NN) ? counts[base + 1] : 0;
  int tsum = v0 + v1;
  s[t] = tsum;
  __syncthreads();
  for (int d = 1; d < ST; d <<= 1) {
    int x = (t >= d) ? s[t - d] : 0;
    __syncthreads();
    s[t] += x;
    __syncthreads();
  }
  int excl = s[t] - tsum;
  if (base < NN) row_ptr[base] = excl;
  if (base + 1 < NN) row_ptr[base + 1] = excl + v0;
  if (t == ST - 1) bsums[b] = s[t];
}

__global__ void k_scan_bsum(const int* __restrict__ bsums, int* __restrict__ boffs,
                            int* __restrict__ row_ptr) {
  __shared__ int s[ST];
  int t = threadIdx.x;
  int v = (t < SB) ? bsums[t] : 0;
  s[t] = v;
  __syncthreads();
  for (int d = 1; d < 256; d <<= 1) {
    int x = (t >= d) ? s[t - d] : 0;
    __syncthreads();
    s[t] += x;
    __syncthreads();
  }
  if (t < SB) boffs[t] = s[t] - v;
  if (t == ST - 1) row_ptr[NN] = s[t];
}

// finalizes row_ptr and initializes per-bucket staging cursors scur[b] = row_ptr[512b]
__global__ void k_scan_add(const int* __restrict__ boffs, int* __restrict__ row_ptr,
                           int* __restrict__ scur) {
  int b = blockIdx.x, t = threadIdx.x;
  int base = b * (ST * SC) + t * SC;
  int o = boffs[b];
  if (base < NN) {
    int v = row_ptr[base] + o;
    row_ptr[base] = v;
    if ((base & 511) == 0) scur[base >> 9] = v;  // bucket base cursor
  }
  if (base + 1 < NN) row_ptr[base + 1] += o;
}

// ---- pass A: chunk edges -> group by 512-node dst-bucket in LDS -> staging ----
__global__ __launch_bounds__(256) void k_bucket(
    const int* __restrict__ ei, const float* __restrict__ attr,
    int* __restrict__ scur, int2* __restrict__ staging) {
  __shared__ int cnt[256], cnt2[256], base[256], gbase[256], s[256];
  __shared__ int lpk[CH];
  __shared__ int lat[CH];
  __shared__ unsigned char lbk[CH];
  const int t = threadIdx.x;
  const int c0 = blockIdx.x * CH;
  const int n = min(CH, NE - c0);
  cnt[t] = 0;
  cnt2[t] = 0;
  __syncthreads();
  for (int k = t; k < n; k += 256) {
    int dst = ei[NE + c0 + k];
    atomicAdd(&cnt[dst >> BKS], 1);
  }
  __syncthreads();
  s[t] = cnt[t];
  __syncthreads();
  for (int d = 1; d < 256; d <<= 1) {
    int x = (t >= d) ? s[t - d] : 0;
    __syncthreads();
    s[t] += x;
    __syncthreads();
  }
  base[t] = s[t] - cnt[t];
  if (cnt[t] > 0) gbase[t] = atomicAdd(&scur[t], cnt[t]);
  __syncthreads();
  for (int k = t; k < n; k += 256) {
    int e = c0 + k;
    int src = ei[e];
    int dst = ei[NE + e];
    int b = dst >> BKS;
    int pos = base[b] + atomicAdd(&cnt2[b], 1);
    lpk[pos] = src | ((dst & 511) << 17);
    lat[pos] = __float_as_int(attr[e]);
    lbk[pos] = (unsigned char)b;
  }
  __syncthreads();
  for (int k = t; k < n; k += 256) {
    int b = lbk[k];
    staging[gbase[b] + (k - base[b])] = make_int2(lpk[k], lat[k]);
  }
}

// ---- pass B: one block per bucket; LDS node cursors; L2-local scatter ----
__global__ __launch_bounds__(256) void k_place(
    const int* __restrict__ row_ptr, const int2* __restrict__ staging,
    int2* __restrict__ csr) {
  __shared__ int cur[512];
  const int b = blockIdx.x;
  const int n0 = b << BKS;
  const int nb = min(512, NN - n0);
  const int t = threadIdx.x;
  for (int j = t; j < nb; j += 256) cur[j] = row_ptr[n0 + j];
  __syncthreads();
  const int s0 = row_ptr[n0];
  const int s1 = row_ptr[n0 + nb];
  for (int i = s0 + t; i < s1; i += 256) {
    int2 r = staging[i];
    int j = ((unsigned)r.x) >> 17;
    int src = r.x & 0x1FFFF;
    int slot = atomicAdd(&cur[j], 1);
    csr[slot] = make_int2(src, r.y);
  }
}

// ------- aggregation: zb = bf16( (1+eps)*hb[n] + sum relu(hb[src]+attr*We+be) ) -------
#define CONS8(hv, at)                                                         \
  do {                                                                        \
    f2 av; av.x = (at); av.y = (at);                                          \
    f2 sx;                                                                    \
    sx = bfpair((hv).x) + (av * we01 + be01);                                 \
    a01 += __builtin_elementwise_max(sx, zero2);                              \
    sx = bfpair((hv).y) + (av * we23 + be23);                                 \
    a23 += __builtin_elementwise_max(sx, zero2);                              \
    sx = bfpair((hv).z) + (av * we45 + be45);                                 \
    a45 += __builtin_elementwise_max(sx, zero2);                              \
    sx = bfpair((hv).w) + (av * we67 + be67);                                 \
    a67 += __builtin_elementwise_max(sx, zero2);                              \
  } while (0)

#define LDROW(s) (*(const uint4*)(hb + (size_t)(s) * DD + d0))

__global__ __launch_bounds__(256) void k_agg(
    const unsigned short* __restrict__ hb,
    const int* __restrict__ row_ptr, const int2* __restrict__ csr,
    const float* __restrict__ We, const float* __restrict__ be,
    const float* __restrict__ epsp, unsigned short* __restrict__ zb) {
  const int tid0 = blockIdx.x * 256 + threadIdx.x;
  const int li = tid0 & 15;
  const int g0 = tid0 >> 4;
  const int NG = (gridDim.x * 256) >> 4;
  const int d0 = li * 8;

  const f2 we01 = *(const f2*)(We + d0);
  const f2 we23 = *(const f2*)(We + d0 + 2);
  const f2 we45 = *(const f2*)(We + d0 + 4);
  const f2 we67 = *(const f2*)(We + d0 + 6);
  const f2 be01 = *(const f2*)(be + d0);
  const f2 be23 = *(const f2*)(be + d0 + 2);
  const f2 be45 = *(const f2*)(be + d0 + 4);
  const f2 be67 = *(const f2*)(be + d0 + 6);
  const float ep = 1.f + epsp[0];
  f2 ep2; ep2.x = ep; ep2.y = ep;
  const f2 zero2 = {0.f, 0.f};

  for (int n = g0; n < NN; n += NG) {
    const int b = row_ptr[n], e = row_ptr[n + 1];
    const int deg = e - b;
    const int cnt = (deg < 16) ? deg : 16;
    int2 rec = (li < cnt) ? csr[b + li] : make_int2(0, 0);
    uint4 hs = LDROW(n);  // self term, issued early
    const int myidx = rec.x;
    const float myatt = __int_as_float(rec.y);
    f2 a01 = zero2, a23 = zero2, a45 = zero2, a67 = zero2;

    {
      int s0 = __shfl(myidx, 0, 16), s1 = __shfl(myidx, 1, 16);
      int s2 = __shfl(myidx, 2, 16), s3 = __shfl(myidx, 3, 16);
      int s4 = __shfl(myidx, 4, 16), s5 = __shfl(myidx, 5, 16);
      int s6 = __shfl(myidx, 6, 16), s7 = __shfl(myidx, 7, 16);
      float t0 = __shfl(myatt, 0, 16), t1 = __shfl(myatt, 1, 16);
      float t2 = __shfl(myatt, 2, 16), t3 = __shfl(myatt, 3, 16);
      float t4 = __shfl(myatt, 4, 16), t5 = __shfl(myatt, 5, 16);
      float t6 = __shfl(myatt, 6, 16), t7 = __shfl(myatt, 7, 16);
      uint4 h0 = LDROW(s0), h1 = LDROW(s1), h2 = LDROW(s2), h3 = LDROW(s3);
      uint4 h4 = LDROW(s4), h5 = LDROW(s5), h6 = LDROW(s6), h7 = LDROW(s7);
      if (cnt > 0) CONS8(h0, t0);
      if (cnt > 1) CONS8(h1, t1);
      if (cnt > 2) CONS8(h2, t2);
      if (cnt > 3) CONS8(h3, t3);
      if (cnt > 4) CONS8(h4, t4);
      if (cnt > 5) CONS8(h5, t5);
      if (cnt > 6) CONS8(h6, t6);
      if (cnt > 7) CONS8(h7, t7);
    }
    if (deg > 8) {
      int s0 = __shfl(myidx, 8, 16), s1 = __shfl(myidx, 9, 16);
      int s2 = __shfl(myidx, 10, 16), s3 = __shfl(myidx, 11, 16);
      int s4 = __shfl(myidx, 12, 16), s5 = __shfl(myidx, 13, 16);
      int s6 = __shfl(myidx, 14, 16), s7 = __shfl(myidx, 15, 16);
      float t0 = __shfl(myatt, 8, 16), t1 = __shfl(myatt, 9, 16);
      float t2 = __shfl(myatt, 10, 16), t3 = __shfl(myatt, 11, 16);
      float t4 = __shfl(myatt, 12, 16), t5 = __shfl(myatt, 13, 16);
      float t6 = __shfl(myatt, 14, 16), t7 = __shfl(myatt, 15, 16);
      uint4 h0 = LDROW(s0), h1 = LDROW(s1), h2 = LDROW(s2), h3 = LDROW(s3);
      uint4 h4 = LDROW(s4), h5 = LDROW(s5), h6 = LDROW(s6), h7 = LDROW(s7);
      if (cnt > 8)  CONS8(h0, t0);
      if (cnt > 9)  CONS8(h1, t1);
      if (cnt > 10) CONS8(h2, t2);
      if (cnt > 11) CONS8(h3, t3);
      if (cnt > 12) CONS8(h4, t4);
      if (cnt > 13) CONS8(h5, t5);
      if (cnt > 14) CONS8(h6, t6);
      if (cnt > 15) CONS8(h7, t7);
      for (int j = b + 16; j < e; j++) {
        int2 r2 = csr[j];
        float a = __int_as_float(r2.y);
        uint4 hv = LDROW(r2.x);
        CONS8(hv, a);
      }
    }

    f2 z01 = ep2 * bfpair(hs.x) + a01;
    f2 z23 = ep2 * bfpair(hs.y) + a23;
    f2 z45 = ep2 * bfpair(hs.z) + a45;
    f2 z67 = ep2 * bfpair(hs.w) + a67;
    uint4 o;
    o.x = (unsigned)f2bf(z01.x) | ((unsigned)f2bf(z01.y) << 16);
    o.y = (unsigned)f2bf(z23.x) | ((unsigned)f2bf(z23.y) << 16);
    o.z = (unsigned)f2bf(z45.x) | ((unsigned)f2bf(z45.y) << 16);
    o.w = (unsigned)f2bf(z67.x) | ((unsigned)f2bf(z67.y) << 16);
    *(uint4*)(zb + (size_t)n * DD + d0) = o;
  }
}

// ---------------- persistent MFMA bf16 GEMM, all-tiles-prefetched (MLP fix) -------
// R8 structure (512 thr, 8 waves = 4 rowblk x 2 colhalf, LDS dbuf), but each block
// owns <=4 tiles and ALL X-tile global loads are issued in the prologue (32 VGPRs
// of prefetch): ~128 KB/CU in flight at issue vs ~16 KB steady-state before ->
// memory system pipelines the full X traffic; no mid-loop load latency.
// MODE 0: z2(bf16) = Xb@W + b, fused column stats (sum,sumsq) -> stats[256]
// MODE 1: Y = relu( relu(bn(Xb))@W + b );       Ybf = bf16(Y) if non-null
// MODE 2: Y = hprev + relu( relu(bn(Xb))@W + b ); same mirror (hprev==Y safe)
template <int MODE>
__global__ __launch_bounds__(512) void k_gemm(
    const unsigned short* __restrict__ Xb, const unsigned short* __restrict__ WT,
    const float* __restrict__ bias, float* __restrict__ stats,
    const float* __restrict__ gamma, const float* __restrict__ beta,
    const float* __restrict__ hprev, float* __restrict__ Yout,
    unsigned short* __restrict__ Ybf) {
  __shared__ unsigned short Wl[128 * 136];     // 34816 B
  __shared__ unsigned short Xl[2][64 * 136];   // 2 x 17408 B
  __shared__ float bns[256];                   // 1024 B -> total 70656 B, 2 blk/CU
  const int tid = threadIdx.x;
  const int G = gridDim.x;
  const int NT = (NN + 63) >> 6;  // 1563

  // stage W^T bf16 [n][k] -> LDS, once per block
  for (int i = tid; i < 2048; i += 512) {
    int rr = i >> 4, c = i & 15;
    *(uint4*)&Wl[rr * 136 + c * 8] = *(const uint4*)&WT[rr * 128 + c * 8];
  }

  const int lane = tid & 63;
  const int w = tid >> 6;        // 0..7
  const int m = lane & 15;
  const int quad = lane >> 4;
  const int rowblk = w & 3;         // which 16-row block of the 64-row tile
  const int ctbase = (w >> 2) * 4;  // ct in [ctbase, ctbase+4): cols ctbase*16..+64

  float4 b4[4];
#pragma unroll
  for (int c = 0; c < 4; c++)
    b4[c] = *(const float4*)&bias[(ctbase + c) * 16 + quad * 4];

  const int c8 = tid & 15, rr16 = tid >> 4;  // staging: lane c8, rows rr16 + it*32
  float scl[8], sfl[8];
  if (MODE >= 1) {
    if (tid < 128) {
      const float invN = 1.f / (float)NN;
      float mu = stats[tid] * invN;
      float var = fmaxf(stats[128 + tid] * invN - mu * mu, 0.f);
      float xx = var + 1e-5f;
      float r = rsqrtf(xx);
      r = r * (1.5f - 0.5f * xx * r * r);  // Newton step
      float scale = gamma[tid] * r;
      bns[tid] = scale;
      bns[128 + tid] = beta[tid] - mu * scale;
    }
    __syncthreads();
#pragma unroll
    for (int j = 0; j < 8; j++) {
      scl[j] = bns[c8 * 8 + j];
      sfl[j] = bns[128 + c8 * 8 + j];
    }
  }

  auto LOADR = [&](uint4 (&xr)[2], int t) {
    int r0 = t << 6;
#pragma unroll
    for (int it = 0; it < 2; it++) {
      int gr = r0 + rr16 + it * 32;
      xr[it] = (gr < NN) ? *(const uint4*)(Xb + (size_t)gr * DD + c8 * 8)
                         : make_uint4(0u, 0u, 0u, 0u);
    }
  };
  auto STORE_LDS = [&](uint4 (&xr)[2], int b) {
#pragma unroll
    for (int it = 0; it < 2; it++) {
      int row = rr16 + it * 32;
      uint4 u = xr[it];
      if (MODE >= 1) {
        unsigned p[4] = {u.x, u.y, u.z, u.w};
#pragma unroll
        for (int j = 0; j < 4; j++) {
          float lo = bf2f((unsigned short)(p[j] & 0xffffu));
          float hi = bf2f((unsigned short)(p[j] >> 16));
          lo = fmaxf(fmaf(lo, scl[2 * j], sfl[2 * j]), 0.f);
          hi = fmaxf(fmaf(hi, scl[2 * j + 1], sfl[2 * j + 1]), 0.f);
          p[j] = (unsigned)f2bf(lo) | ((unsigned)f2bf(hi) << 16);
        }
        u = make_uint4(p[0], p[1], p[2], p[3]);
      }
      *(uint4*)&Xl[b][row * 136 + c8 * 8] = u;
    }
  };

  float4v ssum[4], ssq[4];
  if (MODE == 0) {
#pragma unroll
    for (int c = 0; c < 4; c++) {
      ssum[c] = (float4v){0.f, 0.f, 0.f, 0.f};
      ssq[c] = (float4v){0.f, 0.f, 0.f, 0.f};
    }
  }

  // one tile: MFMA from Xl[bsel], LDS-only fence + barrier, epilogue for tile t.
  auto TILE = [&](int t, int bsel) {
    float4v acc[4];
#pragma unroll
    for (int c = 0; c < 4; c++)
      acc[c] = (float4v){b4[c].x, b4[c].y, b4[c].z, b4[c].w};
    const unsigned short* Ap = &Wl[(ctbase * 16 + m) * 136 + quad * 8];
    const unsigned short* Bp = &Xl[bsel][(rowblk * 16 + m) * 136 + quad * 8];
#pragma unroll
    for (int q = 0; q < 4; q++) {
      short8 bfrag = *(const short8*)(Bp + q * 32);
#pragma unroll
      for (int c = 0; c < 4; c++) {
        short8 afrag = *(const short8*)(Ap + c * 16 * 136 + q * 32);
        acc[c] = __builtin_amdgcn_mfma_f32_16x16x32_bf16(afrag, bfrag, acc[c], 0, 0, 0);
      }
    }
    asm volatile("s_waitcnt lgkmcnt(0)" ::: "memory");
    __builtin_amdgcn_s_barrier();

    const int r = (t << 6) + rowblk * 16 + m;  // this lane's output row
    if (r < NN) {
      const size_t rb = (size_t)r * DD;
      float4 hp[4];
      if (MODE == 2) {  // batch-issue all residual loads before any epilogue math
#pragma unroll
        for (int c = 0; c < 4; c++)
          hp[c] = *(const float4*)&hprev[rb + (ctbase + c) * 16 + quad * 4];
      }
#pragma unroll
      for (int c = 0; c < 4; c++) {
        float4v v = acc[c];
        const int col = (ctbase + c) * 16 + quad * 4;
        if (MODE == 0) {
          ssum[c] += v;
          ssq[c] += v * v;
          ushort4 o;
          o.x = f2bf(v[0]); o.y = f2bf(v[1]); o.z = f2bf(v[2]); o.w = f2bf(v[3]);
          *(ushort4*)&Ybf[rb + col] = o;
        } else {
          v[0] = fmaxf(v[0], 0.f); v[1] = fmaxf(v[1], 0.f);
          v[2] = fmaxf(v[2], 0.f); v[3] = fmaxf(v[3], 0.f);
          if (MODE == 2) {
            v[0] += hp[c].x; v[1] += hp[c].y; v[2] += hp[c].z; v[3] += hp[c].w;
          }
          *(float4v*)&Yout[rb + col] = v;
          if (Ybf) {
            ushort4 o;
            o.x = f2bf(v[0]); o.y = f2bf(v[1]); o.z = f2bf(v[2]); o.w = f2bf(v[3]);
            *(ushort4*)&Ybf[rb + col] = o;
          }
        }
      }
    }
  };

  // ---- prologue: issue ALL of this block's X loads (<=4 tiles, 32 VGPRs) ----
  const int t0 = blockIdx.x;
  const int t1 = t0 + G, t2 = t0 + 2 * G, t3 = t0 + 3 * G;
  uint4 x0[2], x1[2], x2[2], x3[2];
  LOADR(x0, t0);
  if (t1 < NT) LOADR(x1, t1);
  if (t2 < NT) LOADR(x2, t2);
  if (t3 < NT) LOADR(x3, t3);
  STORE_LDS(x0, 0);
  __syncthreads();  // Xl[0] + Wl ready

  // ---- statically scheduled tile sequence (dbuf 0,1,0,1) ----
  if (t1 < NT) STORE_LDS(x1, 1);
  TILE(t0, 0);
  if (t1 < NT) {
    if (t2 < NT) STORE_LDS(x2, 0);
    TILE(t1, 1);
    if (t2 < NT) {
      if (t3 < NT) STORE_LDS(x3, 1);
      TILE(t2, 0);
      if (t3 < NT) TILE(t3, 1);
    }
  }

  if (MODE == 0) {
    // per-wave reduce over the 16 m-lanes, partials to LDS scratch [8][64],
    // then 128 threads fold the 4 row-block waves per column half -> 256 atomics.
    float* sarr = (float*)Xl;    // [8][64]
    float* sqarr = sarr + 512;   // [8][64]
#pragma unroll
    for (int c = 0; c < 4; c++) {
      float4v s = ssum[c], s2 = ssq[c];
#pragma unroll
      for (int d = 1; d < 16; d <<= 1) {
#pragma unroll
        for (int j = 0; j < 4; j++) {
          s[j] += __shfl_xor(s[j], d);
          s2[j] += __shfl_xor(s2[j], d);
        }
      }
      if (m == 0) {
        *(float4v*)&sarr[w * 64 + c * 16 + quad * 4] = s;
        *(float4v*)&sqarr[w * 64 + c * 16 + quad * 4] = s2;
      }
    }
    __syncthreads();
    if (tid < 128) {
      const int ch = tid >> 6;
      const int cl = tid & 63;
      float s = 0.f, s2 = 0.f;
#pragma unroll
      for (int ww = 0; ww < 4; ww++) {
        s += sarr[(ch * 4 + ww) * 64 + cl];
        s2 += sqarr[(ch * 4 + ww) * 64 + cl];
      }
      atomicAdd(&stats[tid], s);
      atomicAdd(&stats[128 + tid], s2);
    }
  }
}

// ---------------- driver ----------------
static inline size_t align256(size_t x) { return (x + 255) & ~(size_t)255; }

extern "C" void kernel_launch(void* const* d_in, const int* in_sizes, int n_in,
                              void* d_out, int out_size, void* d_ws, size_t ws_size,
                              hipStream_t stream) {
  const float* x     = (const float*)d_in[0];
  const int*   ei    = (const int*)d_in[1];
  const float* attr  = (const float*)d_in[2];
  const float* We    = (const float*)d_in[3];
  const float* be    = (const float*)d_in[4];
  const float* eps   = (const float*)d_in[5];
  const float* W1    = (const float*)d_in[6];
  const float* b1    = (const float*)d_in[7];
  const float* gamma = (const float*)d_in[8];
  const float* beta  = (const float*)d_in[9];
  const float* W2    = (const float*)d_in[10];
  const float* b2    = (const float*)d_in[11];
  float* out = (float*)d_out;

  char* w = (char*)d_ws;
  unsigned short* z2 = (unsigned short*)w; w += align256((size_t)NN * DD * 2);
  unsigned short* hb = (unsigned short*)w; w += align256((size_t)NN * DD * 2);
  unsigned short* zb = (unsigned short*)w; w += align256((size_t)NN * DD * 2);
  int*   row_ptr  = (int*)w;   w += align256((size_t)(NN + 1) * 4);
  int*   counts   = (int*)w;   w += align256((size_t)NN * 4);
  int*   scur     = (int*)w;   w += align256(256 * 4);
  int2*  csr      = (int2*)w;  w += align256((size_t)NE * 8);
  int2*  staging  = (int2*)w;  w += align256((size_t)NE * 8);
  float* stats4   = (float*)w; w += align256((size_t)NL * 256 * 4);
  int*   bsums    = (int*)w;   w += align256(ST * 4);
  int*   boffs    = (int*)w;   w += align256(ST * 4);
  unsigned short* WTb = (unsigned short*)w; w += align256((size_t)8 * 16384 * 2);

  // weight prep (zeroes counts+stats) -> h2b (fused edge count) -> CSR build
  k_prep<<<512, 256, 0, stream>>>(W1, W2, WTb, counts, stats4);
  k_h2b<<<(NN * DD / 4 + 255) / 256, 256, 0, stream>>>(x, hb, ei, counts);
  k_scan_part<<<SB, ST, 0, stream>>>(counts, row_ptr, bsums);
  k_scan_bsum<<<1, ST, 0, stream>>>(bsums, boffs, row_ptr);
  k_scan_add<<<SB, ST, 0, stream>>>(boffs, row_ptr, scur);
  k_bucket<<<(NE + CH - 1) / CH, 256, 0, stream>>>(ei, attr, scur, staging);
  k_place<<<NBK, 256, 0, stream>>>(row_ptr, staging, csr);

  for (int l = 0; l < NL; l++) {
    float* st = stats4 + (size_t)l * 256;
    k_agg<<<2048, 256, 0, stream>>>(
        hb, row_ptr, csr, We + l * DD, be + l * DD, eps + l, zb);
    // z2(bf16) = zb @ W1 + b1, fused stats
    k_gemm<0><<<GB, 512, 0, stream>>>(zb, WTb + (size_t)l * 16384, b1 + l * DD,
                                      st, nullptr, nullptr, nullptr, nullptr, z2);
    unsigned short* hbo = (l < NL - 1) ? hb : nullptr;
    if (l == 0)
      k_gemm<1><<<GB, 512, 0, stream>>>(z2, WTb + (size_t)(4 + l) * 16384, b2 + l * DD,
                                        st, gamma + l * DD, beta + l * DD,
                                        nullptr, out, hbo);
    else
      k_gemm<2><<<GB, 512, 0, stream>>>(z2, WTb + (size_t)(4 + l) * 16384, b2 + l * DD,
                                        st, gamma + l * DD, beta + l * DD,
                                        out, out, hbo);
  }
}